// Round 8
// baseline (311.772 us; speedup 1.0000x reference)
//
#include <hip/hip_runtime.h>
#include <hip/hip_bf16.h>
#include <hip/hip_fp16.h>
#include <math.h>

constexpr int N_NODES = 50000;
constexpr int N_EDGES = 850000;
constexpr int HDIM = 128;   // H*D
constexpr int AGG_BLOCKS = N_NODES / 8;  // 6250
constexpr int BN_BUCKETS = 16;

typedef _Float16 f16x8 __attribute__((ext_vector_type(8)));
typedef float f32x4 __attribute__((ext_vector_type(4)));

// v_fma_mix_f32: acc += f16(lo/hi of pk) * w   (exact f16->f32 convert inside FMA)
#define FMAMIX_LO(acc, pk, w) \
    asm("v_fma_mix_f32 %0, %1, %2, %0 op_sel:[0,0,0] op_sel_hi:[1,0,0]" \
        : "+v"(acc) : "v"(pk), "v"(w))
#define FMAMIX_HI(acc, pk, w) \
    asm("v_fma_mix_f32 %0, %1, %2, %0 op_sel:[1,0,0] op_sel_hi:[1,0,0]" \
        : "+v"(acc) : "v"(pk), "v"(w))

__device__ __forceinline__ float elu1(float t) {
    return (t > 0.f) ? t : (__expf(t) - 1.f);
}

// ---------------- CSR build params ----------------
constexpr int NB2 = 128;                                // buckets
constexpr int RANGE2 = (N_NODES + NB2 - 1) / NB2;       // 391 nodes/bucket
constexpr int CAP = 8192;                               // bucket capacity (avg 6641)
constexpr int CHUNK = 8192;                             // edges per phase-A block
constexpr int GA = (N_EDGES + CHUNK - 1) / CHUNK;       // 104 blocks
constexpr int WPACK_BLOCKS = 6;                          // 6*1024 = 6144 = 3*2048
constexpr int GEMM0_BLOCKS = (N_NODES + 255) / 256;      // 196
constexpr int FUSEB_BLOCKS = GEMM0_BLOCKS + NB2;         // 324

// ---------------- fused dispatch A: partA (CSR phase 1) || wpack ----------------
__global__ void k_fuseA(const int* __restrict__ src, const int* __restrict__ dst,
                        int* __restrict__ g_cursor, unsigned* __restrict__ bucket,
                        const float* __restrict__ W0, const float* __restrict__ W1,
                        const float* __restrict__ W2, __half* __restrict__ wpk,
                        float* __restrict__ bn_part) {
    __shared__ int hist[NB2];
    int tid = threadIdx.x;
    if (blockIdx.x < GA) {
        // ---- partA: bucket edges by dst range ----
        int e0 = blockIdx.x * CHUNK;
        int e1 = min(e0 + CHUNK, N_EDGES);
        if (tid < NB2) hist[tid] = 0;
        __syncthreads();
        for (int i = e0 + tid; i < e1; i += 1024) {
            int d = dst[i];
            atomicAdd(&hist[d / RANGE2], 1);
        }
        __syncthreads();
        int base = 0;
        if (tid < NB2) base = atomicAdd(&g_cursor[tid], hist[tid]);
        __syncthreads();
        if (tid < NB2) hist[tid] = base;
        __syncthreads();
        for (int i = e0 + tid; i < e1; i += 1024) {
            int d = dst[i];
            int s = src[i];
            int b = d / RANGE2;
            int p = atomicAdd(&hist[b], 1);
            bucket[b * CAP + p] = (unsigned)s | ((unsigned)(d - b * RANGE2) << 16);
        }
    } else {
        // ---- wpack: W -> MFMA B-fragment layout; zero bn_part ----
        int gid = (blockIdx.x - GA) * 1024 + tid;  // [0, 6144)
        int z0 = gid * 8;
        if (z0 < 3 * BN_BUCKETS * 256) {
            float4 z = make_float4(0.f, 0.f, 0.f, 0.f);
            *reinterpret_cast<float4*>(&bn_part[z0]) = z;
            *reinterpret_cast<float4*>(&bn_part[z0 + 4]) = z;
        }
        if (gid >= 3 * 2048) return;
        int L = gid >> 11;
        int rem = gid & 2047;
        int ct = rem >> 8;
        int kc = (rem >> 6) & 3;
        int l = rem & 63;
        const float* W = (L == 0) ? W0 : ((L == 1) ? W1 : W2);
        int c = ct * 16 + (l & 15);
        int k0 = kc * 32 + (l >> 4) * 8;
        __half tmp[8];
#pragma unroll
        for (int j = 0; j < 8; j++) tmp[j] = __float2half(W[(k0 + j) * HDIM + c]);
        *reinterpret_cast<float4*>(&wpk[((size_t)L << 14) +
                                        ((size_t)(ct * 4 + kc) * 64 + l) * 8]) =
            *reinterpret_cast<float4*>(tmp);
    }
}

// ---------------- fused dispatch B: gemm layer-0 (mode0, 256 nodes/block) || partB ----------------
__global__ void k_fuseB(const int* __restrict__ xidx, const float* __restrict__ embed,
                        const f16x8* __restrict__ wB, __half* __restrict__ feat_h,
                        const float* __restrict__ al, const float* __restrict__ ar,
                        float* __restrict__ el, float* __restrict__ er,
                        const unsigned* __restrict__ bucket, const int* __restrict__ cnts,
                        int* __restrict__ rowstart, int* __restrict__ esrc) {
    __shared__ __align__(16) char smem[16 * 16 * 136 * 2];  // 69.6 KB, aliased per branch
    int tid = threadIdx.x;
    if (blockIdx.x < GEMM0_BLOCKS) {
        // ---- gemm0: feat = embed[x] @ W0 (MFMA), fused el/er; 16 waves, 256 nodes ----
        __half (*sf)[16][136] = reinterpret_cast<__half (*)[16][136]>(smem);
        int w = tid >> 6, lane = tid & 63;
        int r = lane & 15, kg = lane >> 4;
        int wbase = blockIdx.x * 256 + w * 16;
        int n = wbase + r;
        bool ok = n < N_NODES;
        f16x8 aF[4];
#pragma unroll
        for (int kc = 0; kc < 4; kc++)
#pragma unroll
            for (int j = 0; j < 8; j++) aF[kc][j] = (_Float16)0.f;
        if (ok) {
            int xi = xidx[n];
            const float* ep = embed + (size_t)xi * HDIM;
#pragma unroll
            for (int kc = 0; kc < 4; kc++) {
                int c0 = kc * 32 + kg * 8;
                float4 e0 = *reinterpret_cast<const float4*>(ep + c0);
                float4 e1 = *reinterpret_cast<const float4*>(ep + c0 + 4);
                aF[kc][0] = (_Float16)e0.x; aF[kc][1] = (_Float16)e0.y;
                aF[kc][2] = (_Float16)e0.z; aF[kc][3] = (_Float16)e0.w;
                aF[kc][4] = (_Float16)e1.x; aF[kc][5] = (_Float16)e1.y;
                aF[kc][6] = (_Float16)e1.z; aF[kc][7] = (_Float16)e1.w;
            }
        }
        f32x4 acc[8] = {};
#pragma unroll
        for (int kc = 0; kc < 4; kc++) {
#pragma unroll
            for (int ct = 0; ct < 8; ct++) {
                f16x8 bF = wB[(ct * 4 + kc) * 64 + lane];
                acc[ct] = __builtin_amdgcn_mfma_f32_16x16x32_f16(aF[kc], bF, acc[ct], 0, 0, 0);
            }
        }
#pragma unroll
        for (int ct = 0; ct < 8; ct++)
#pragma unroll
            for (int reg = 0; reg < 4; reg++)
                sf[w][kg * 4 + reg][ct * 16 + r] = __float2half(acc[ct][reg]);
        __syncthreads();
        float alq[8], arq[8];
        {
            float4 a0 = *reinterpret_cast<const float4*>(&al[r * 8]);
            float4 a1 = *reinterpret_cast<const float4*>(&al[r * 8 + 4]);
            float4 b0 = *reinterpret_cast<const float4*>(&ar[r * 8]);
            float4 b1 = *reinterpret_cast<const float4*>(&ar[r * 8 + 4]);
            alq[0] = a0.x; alq[1] = a0.y; alq[2] = a0.z; alq[3] = a0.w;
            alq[4] = a1.x; alq[5] = a1.y; alq[6] = a1.z; alq[7] = a1.w;
            arq[0] = b0.x; arq[1] = b0.y; arq[2] = b0.z; arq[3] = b0.w;
            arq[4] = b1.x; arq[5] = b1.y; arq[6] = b1.z; arq[7] = b1.w;
        }
#pragma unroll
        for (int q = 0; q < 4; q++) {
            int row = q * 4 + kg;
            int n2 = wbase + row;
            float4 v = *reinterpret_cast<const float4*>(&sf[w][row][r * 8]);
            if (n2 < N_NODES)
                *reinterpret_cast<float4*>(&feat_h[(size_t)n2 * HDIM + r * 8]) = v;
            const __half2* u = reinterpret_cast<const __half2*>(&v);
            float pl = 0.f, pr = 0.f;
#pragma unroll
            for (int t = 0; t < 4; t++) {
                float lo = __half2float(__low2half(u[t]));
                float hi = __half2float(__high2half(u[t]));
                pl += lo * alq[2 * t] + hi * alq[2 * t + 1];
                pr += lo * arq[2 * t] + hi * arq[2 * t + 1];
            }
            pl += __shfl_xor(pl, 1, 64); pr += __shfl_xor(pr, 1, 64);
            pl += __shfl_xor(pl, 2, 64); pr += __shfl_xor(pr, 2, 64);
            if ((r & 3) == 0 && n2 < N_NODES) {
                int head = r >> 2;
                el[n2 * 4 + head] = pl;
                er[n2 * 4 + head] = pr;
            }
        }
    } else {
        // ---- partB: per-bucket counting sort -> rowstart/esrc ----
        int* cnt_s = reinterpret_cast<int*>(smem);            // 128
        int* hist = cnt_s + NB2;                               // 391
        int* lcur = hist + RANGE2;                             // 391
        int* wsum = lcur + RANGE2;                             // 7
        int b = blockIdx.x - GEMM0_BLOCKS;
        int lo = b * RANGE2;
        int myCount = cnts[b];
        if (tid < NB2) cnt_s[tid] = cnts[tid];
        __syncthreads();
        for (int off = 1; off < NB2; off <<= 1) {
            int t = (tid < NB2 && tid >= off) ? cnt_s[tid - off] : 0;
            __syncthreads();
            if (tid < NB2) cnt_s[tid] += t;
            __syncthreads();
        }
        int base = cnt_s[b] - myCount;
        for (int j = tid; j < RANGE2; j += 1024) hist[j] = 0;
        __syncthreads();
        const unsigned* my = bucket + (size_t)b * CAP;
        for (int i = tid; i < myCount; i += 1024) atomicAdd(&hist[my[i] >> 16], 1);
        __syncthreads();
        int v = 0;
        if (tid < 448) v = (tid < RANGE2) ? hist[tid] : 0;
        int inc = v;
        int lane = tid & 63;
#pragma unroll
        for (int off = 1; off < 64; off <<= 1) {
            int t = __shfl_up(inc, off, 64);
            if (lane >= off) inc += t;
        }
        if (tid < 448 && lane == 63) wsum[tid >> 6] = inc;
        __syncthreads();
        if (tid < RANGE2) {
            int woff = 0;
            for (int w = 0; w < (tid >> 6); w++) woff += wsum[w];
            int excl = woff + inc - v;
            lcur[tid] = excl;
            int node = lo + tid;
            if (node < N_NODES) rowstart[node] = base + excl;
        }
        if (b == 0 && tid == 0) rowstart[N_NODES] = N_EDGES;
        __syncthreads();
        for (int i = tid; i < myCount; i += 1024) {
            unsigned p = my[i];
            int pos = atomicAdd(&lcur[p >> 16], 1);
            esrc[base + pos] = (int)(p & 0xFFFFu);
        }
    }
}

// ---------------- GEMM v6: MFMA 16x16x32_f16, BN finalize fused in prologue (L1/L2) ----------------
__global__ void k_gemm6(const __half* __restrict__ h, const f16x8* __restrict__ wB,
                        __half* __restrict__ feat_h, const float* __restrict__ bn_prev,
                        const float* __restrict__ gamma, const float* __restrict__ beta,
                        const float* __restrict__ al, const float* __restrict__ ar,
                        float* __restrict__ el, float* __restrict__ er) {
    __shared__ __half sf[4][16][136];  // per-wave 16x128 fp16 tile (+8 pad), 17.4 KB
    __shared__ __align__(16) float s_sc[128];
    __shared__ __align__(16) float s_sh[128];
    int tid = threadIdx.x;
    // ---- BN finalize prologue (redundant per block; bn_prev is L2-resident 16 KB) ----
    {
        float* red = reinterpret_cast<float*>(sf);   // alias; sf written after
        int c = tid & 127, which = tid >> 7;
        float t = 0.f;
#pragma unroll
        for (int b = 0; b < BN_BUCKETS; b++) t += bn_prev[b * 256 + which * 128 + c];
        red[tid] = t;
        __syncthreads();
        if (tid < 128) {
            float mu = red[tid] * (1.f / N_NODES);
            float var = red[128 + tid] * (1.f / N_NODES) - mu * mu;
            float sc = gamma[tid] * rsqrtf(var + 1e-5f);
            s_sc[tid] = sc;
            s_sh[tid] = beta[tid] - mu * sc;
        }
        __syncthreads();
    }
    int w = tid >> 6, lane = tid & 63;
    int r = lane & 15, kg = lane >> 4;
    int wbase = blockIdx.x * 64 + w * 16;
    int n = wbase + r;
    bool ok = n < N_NODES;

    f16x8 aF[4];
#pragma unroll
    for (int kc = 0; kc < 4; kc++)
#pragma unroll
        for (int j = 0; j < 8; j++) aF[kc][j] = (_Float16)0.f;
    if (ok) {
        const __half* hp = h + (size_t)n * HDIM;
#pragma unroll
        for (int kc = 0; kc < 4; kc++) {
            int c0 = kc * 32 + kg * 8;
            float4 raw = *reinterpret_cast<const float4*>(hp + c0);
            const __half2* u = reinterpret_cast<const __half2*>(&raw);
            float4 sc0 = *reinterpret_cast<const float4*>(&s_sc[c0]);
            float4 sc1 = *reinterpret_cast<const float4*>(&s_sc[c0 + 4]);
            float4 sh0 = *reinterpret_cast<const float4*>(&s_sh[c0]);
            float4 sh1 = *reinterpret_cast<const float4*>(&s_sh[c0 + 4]);
            float scv[8] = {sc0.x, sc0.y, sc0.z, sc0.w, sc1.x, sc1.y, sc1.z, sc1.w};
            float shv[8] = {sh0.x, sh0.y, sh0.z, sh0.w, sh1.x, sh1.y, sh1.z, sh1.w};
            float vv[8];
#pragma unroll
            for (int t = 0; t < 4; t++) {
                vv[2 * t] = __half2float(__low2half(u[t]));
                vv[2 * t + 1] = __half2float(__high2half(u[t]));
            }
#pragma unroll
            for (int j = 0; j < 8; j++) {
                float t = vv[j] * scv[j] + shv[j];
                aF[kc][j] = (_Float16)elu1(t);
            }
        }
    }
    __syncthreads();  // red alias done before sf writes

    f32x4 acc[8] = {};
#pragma unroll
    for (int kc = 0; kc < 4; kc++) {
#pragma unroll
        for (int ct = 0; ct < 8; ct++) {
            f16x8 bF = wB[(ct * 4 + kc) * 64 + lane];
            acc[ct] = __builtin_amdgcn_mfma_f32_16x16x32_f16(aF[kc], bF, acc[ct], 0, 0, 0);
        }
    }

#pragma unroll
    for (int ct = 0; ct < 8; ct++)
#pragma unroll
        for (int reg = 0; reg < 4; reg++)
            sf[w][kg * 4 + reg][ct * 16 + r] = __float2half(acc[ct][reg]);
    __syncthreads();
    float alq[8], arq[8];
    {
        float4 a0 = *reinterpret_cast<const float4*>(&al[r * 8]);
        float4 a1 = *reinterpret_cast<const float4*>(&al[r * 8 + 4]);
        float4 b0 = *reinterpret_cast<const float4*>(&ar[r * 8]);
        float4 b1 = *reinterpret_cast<const float4*>(&ar[r * 8 + 4]);
        alq[0] = a0.x; alq[1] = a0.y; alq[2] = a0.z; alq[3] = a0.w;
        alq[4] = a1.x; alq[5] = a1.y; alq[6] = a1.z; alq[7] = a1.w;
        arq[0] = b0.x; arq[1] = b0.y; arq[2] = b0.z; arq[3] = b0.w;
        arq[4] = b1.x; arq[5] = b1.y; arq[6] = b1.z; arq[7] = b1.w;
    }
#pragma unroll
    for (int q = 0; q < 4; q++) {
        int row = q * 4 + kg;
        int n2 = wbase + row;
        float4 v = *reinterpret_cast<const float4*>(&sf[w][row][r * 8]);
        if (n2 < N_NODES)
            *reinterpret_cast<float4*>(&feat_h[(size_t)n2 * HDIM + r * 8]) = v;
        const __half2* u = reinterpret_cast<const __half2*>(&v);
        float pl = 0.f, pr = 0.f;
#pragma unroll
        for (int t = 0; t < 4; t++) {
            float lo = __half2float(__low2half(u[t]));
            float hi = __half2float(__high2half(u[t]));
            pl += lo * alq[2 * t] + hi * alq[2 * t + 1];
            pr += lo * arq[2 * t] + hi * arq[2 * t + 1];
        }
        pl += __shfl_xor(pl, 1, 64); pr += __shfl_xor(pr, 1, 64);
        pl += __shfl_xor(pl, 2, 64); pr += __shfl_xor(pr, 2, 64);
        if ((r & 3) == 0 && n2 < N_NODES) {
            int head = r >> 2;
            el[n2 * 4 + head] = pl;
            er[n2 * 4 + head] = pr;
        }
    }
}

// ---------------- aggregation v13: 8-deep remainder-free gather pipeline ----------------
// All 32 LDS slots per chunk are always written (w=0 beyond deg, clamped src index),
// so iters can be rounded up to a multiple of 8 (<=16): wasted slots contribute exactly
// 0 and their gathers duplicate the last real row (L2 hits).
__global__ void k_agg13(const __half* __restrict__ feat_h, const float* __restrict__ el,
                        const float* __restrict__ er, const int* __restrict__ rowstart,
                        const int* __restrict__ esrc, const float* __restrict__ snorm_n,
                        __half* __restrict__ h, const float* __restrict__ bn_prev,
                        const float* __restrict__ gamma, const float* __restrict__ beta,
                        float* __restrict__ bn_cur, int layer) {
    __shared__ __align__(16) int2 lds[4][2][2][32][4];  // [wave][h2][buf][slot][head], 16 KB
    __shared__ __align__(16) float s_sc[128];
    __shared__ __align__(16) float s_sh[128];
    int tid = threadIdx.x;
    if (layer > 0) {
        float* red = reinterpret_cast<float*>(lds);  // alias; lds rewritten after barrier
        int c = tid & 127, which = tid >> 7;
        float t = 0.f;
#pragma unroll
        for (int b = 0; b < BN_BUCKETS; b++) t += bn_prev[b * 256 + which * 128 + c];
        red[tid] = t;
        __syncthreads();
        if (tid < 128) {
            float mu = red[tid] * (1.f / N_NODES);
            float var = red[128 + tid] * (1.f / N_NODES) - mu * mu;
            float sc = gamma[tid] * rsqrtf(var + 1e-5f);
            s_sc[tid] = sc;
            s_sh[tid] = beta[tid] - mu * sc;
        }
        __syncthreads();
    }
    int wave = tid >> 6, lane = tid & 63;
    int h2 = lane >> 5, hl = lane & 31;
    int dp = hl & 15, epair = hl >> 4, head = dp >> 2;
    unsigned dpo = (unsigned)dp << 4;
    const char* fb = reinterpret_cast<const char*>(feat_h);
    const char* eb = reinterpret_cast<const char*>(el);
    int n = blockIdx.x * 8 + wave * 2 + h2;
    int e0 = rowstart[n];
    int deg = rowstart[n + 1] - e0;
    int dmax = max(deg, __shfl_xor(deg, 32, 64));
    float4 er4 = *(const float4*)&er[n * 4];
    float s = 0.f;
    float a[8] = {};
    int nch = (dmax + 31) >> 5;

    int idx0 = e0 + min(hl, deg - 1);
    int sidx_p = esrc[idx0];
    float4 el_p = *reinterpret_cast<const float4*>(eb + ((unsigned)sidx_p << 4));
    bool val_p = hl < deg;

    for (int c = 0; c < nch; c++) {
        float w0 = 0.f, w1 = 0.f, w2 = 0.f, w3 = 0.f;
        int sv = sidx_p;
        if (val_p) {
            float ex = el_p.x + er4.x, ey = el_p.y + er4.y;
            float ez = el_p.z + er4.z, ew = el_p.w + er4.w;
            ex = fmaxf(ex, 0.f) + 0.2f * fminf(ex, 0.f);
            ey = fmaxf(ey, 0.f) + 0.2f * fminf(ey, 0.f);
            ez = fmaxf(ez, 0.f) + 0.2f * fminf(ez, 0.f);
            ew = fmaxf(ew, 0.f) + 0.2f * fminf(ew, 0.f);
            w0 = __expf(ex); w1 = __expf(ey); w2 = __expf(ez); w3 = __expf(ew);
        }
        int4* wp = reinterpret_cast<int4*>(&lds[wave][h2][c & 1][hl][0]);
        wp[0] = make_int4(sv, __float_as_int(w0), sv, __float_as_int(w1));
        wp[1] = make_int4(sv, __float_as_int(w2), sv, __float_as_int(w3));
        if (c + 1 < nch) {
            int slot = (c + 1) * 32 + hl;
            int idx = e0 + min(slot, deg - 1);
            sidx_p = esrc[idx];
            el_p = *reinterpret_cast<const float4*>(eb + ((unsigned)sidx_p << 4));
            val_p = slot < deg;
        }
        int cnt = min(32, dmax - c * 32);
        int iters = (cnt + 1) >> 1;          // pairs actually needed
        int itr8 = (iters + 7) & ~7;         // round up to 8; <=16, all slots valid
        const int2 (*slot_p)[4] = lds[wave][h2][c & 1];
#pragma unroll 1
        for (int j = 0; j < itr8; j += 8) {
            int2 rr[8];
#pragma unroll
            for (int q = 0; q < 8; q++) rr[q] = slot_p[(j + q) * 2 + epair][head];
            uint4 uu[8];
#pragma unroll
            for (int q = 0; q < 8; q++)
                uu[q] = *reinterpret_cast<const uint4*>(fb + (((unsigned)rr[q].x << 8) + dpo));
#pragma unroll
            for (int q = 0; q < 8; q++) {
                float w = __int_as_float(rr[q].y);
                FMAMIX_LO(a[0], uu[q].x, w); FMAMIX_HI(a[1], uu[q].x, w);
                FMAMIX_LO(a[2], uu[q].y, w); FMAMIX_HI(a[3], uu[q].y, w);
                FMAMIX_LO(a[4], uu[q].z, w); FMAMIX_HI(a[5], uu[q].z, w);
                FMAMIX_LO(a[6], uu[q].w, w); FMAMIX_HI(a[7], uu[q].w, w);
                s += w;
            }
        }
    }
#pragma unroll
    for (int k = 0; k < 8; k++) a[k] += __shfl_xor(a[k], 16, 64);
    s += __shfl_xor(s, 16, 64);
    float r[8] = {};
    if (epair == 0) {
        float inv = 1.f / s;
        int d0 = dp * 8;
#pragma unroll
        for (int k = 0; k < 8; k++) r[k] = a[k] * inv;
        if (layer > 0) {
            float4 hraw = *reinterpret_cast<const float4*>(&h[(size_t)n * HDIM + d0]);
            __half2 q0 = *(__half2*)&hraw.x, q1 = *(__half2*)&hraw.y;
            __half2 q2 = *(__half2*)&hraw.z, q3 = *(__half2*)&hraw.w;
            float hv[8] = {__half2float(__low2half(q0)), __half2float(__high2half(q0)),
                           __half2float(__low2half(q1)), __half2float(__high2half(q1)),
                           __half2float(__low2half(q2)), __half2float(__high2half(q2)),
                           __half2float(__low2half(q3)), __half2float(__high2half(q3))};
            float4 sc0 = *reinterpret_cast<const float4*>(&s_sc[d0]);
            float4 sc1 = *reinterpret_cast<const float4*>(&s_sc[d0 + 4]);
            float4 sh0 = *reinterpret_cast<const float4*>(&s_sh[d0]);
            float4 sh1 = *reinterpret_cast<const float4*>(&s_sh[d0 + 4]);
            float scv[8] = {sc0.x, sc0.y, sc0.z, sc0.w, sc1.x, sc1.y, sc1.z, sc1.w};
            float shv[8] = {sh0.x, sh0.y, sh0.z, sh0.w, sh1.x, sh1.y, sh1.z, sh1.w};
#pragma unroll
            for (int k = 0; k < 8; k++) {
                float t = hv[k] * scv[k] + shv[k];
                r[k] += elu1(t);
                r[k] = elu1(r[k]);
            }
        }
        float sn = snorm_n[n];
#pragma unroll
        for (int k = 0; k < 8; k++) r[k] *= sn;
        float4 outv;
        *(__half2*)&outv.x = __floats2half2_rn(r[0], r[1]);
        *(__half2*)&outv.y = __floats2half2_rn(r[2], r[3]);
        *(__half2*)&outv.z = __floats2half2_rn(r[4], r[5]);
        *(__half2*)&outv.w = __floats2half2_rn(r[6], r[7]);
        *reinterpret_cast<float4*>(&h[(size_t)n * HDIM + d0]) = outv;
    }

    float* bsum = reinterpret_cast<float*>(lds);
    __syncthreads();
    if (epair == 0) {
        int n8 = wave * 2 + h2;
        int cbase = n8 * 128 + dp * 8;
#pragma unroll
        for (int k = 0; k < 8; k++) {
            bsum[cbase + k] = r[k];
            bsum[1024 + cbase + k] = r[k] * r[k];
        }
    }
    __syncthreads();
    {
        int c = tid & 127, which = tid >> 7;
        float v = 0.f;
#pragma unroll
        for (int n8 = 0; n8 < 8; n8++) v += bsum[which * 1024 + n8 * 128 + c];
        atomicAdd(&bn_cur[(blockIdx.x & (BN_BUCKETS - 1)) * 256 + which * 128 + c], v);
    }
}

// ---------------- classifier (h fp16), BN finalize fused ----------------
__global__ void k_classifier(const __half* __restrict__ h, const float* __restrict__ W1,
                             const float* __restrict__ b1, const float* __restrict__ W2,
                             const float* __restrict__ b2, const float* __restrict__ bn_prev,
                             const float* __restrict__ gamma, const float* __restrict__ beta,
                             float* __restrict__ out) {
    __shared__ float hs[16][128];
    __shared__ __align__(16) float s_sc[128];
    __shared__ __align__(16) float s_sh[128];
    int tid = threadIdx.x;
    {
        float* red = &hs[0][0];
        int c = tid & 127, which = tid >> 7;
        float t = 0.f;
#pragma unroll
        for (int b = 0; b < BN_BUCKETS; b++) t += bn_prev[b * 256 + which * 128 + c];
        red[tid] = t;
        __syncthreads();
        if (tid < 128) {
            float mu = red[tid] * (1.f / N_NODES);
            float var = red[128 + tid] * (1.f / N_NODES) - mu * mu;
            float sc = gamma[tid] * rsqrtf(var + 1e-5f);
            s_sc[tid] = sc;
            s_sh[tid] = beta[tid] - mu * sc;
        }
        __syncthreads();
    }
    int nbase = blockIdx.x * 16;
    for (int i = tid; i < 16 * 128; i += 256) {
        int r = i >> 7, c = i & 127;
        int n = nbase + r;
        float v = 0.f;
        if (n < N_NODES) {
            v = __half2float(h[(size_t)n * HDIM + c]) * s_sc[c] + s_sh[c];
            v = elu1(v);
        }
        hs[r][c] = v;
    }
    __syncthreads();
    int j = tid & 63;
    int g = tid >> 6;
    float bj = b1[j];
    float acc[4] = {bj, bj, bj, bj};
    for (int k = 0; k < 128; k++) {
        float w = W1[k * 64 + j];
#pragma unroll
        for (int i = 0; i < 4; i++) acc[i] += hs[g * 4 + i][k] * w;
    }
    float w20 = W2[j * 2], w21 = W2[j * 2 + 1];
    float res[8];
#pragma unroll
    for (int i = 0; i < 4; i++) {
        float hid = fmaxf(acc[i], 0.f);
        res[2 * i] = hid * w20;
        res[2 * i + 1] = hid * w21;
    }
#pragma unroll
    for (int off = 1; off < 64; off <<= 1)
#pragma unroll
        for (int i = 0; i < 8; i++) res[i] += __shfl_xor(res[i], off, 64);
    if (j < 8) {
        int n = nbase + g * 4 + (j >> 1);
        if (n < N_NODES) out[n * 2 + (j & 1)] = res[j] + b2[j & 1];
    }
}

// ----------------------------------------------------------------
extern "C" void kernel_launch(void* const* d_in, const int* in_sizes, int n_in,
                              void* d_out, int out_size, void* d_ws, size_t ws_size,
                              hipStream_t stream) {
    const int* x = (const int*)d_in[0];
    const int* src = (const int*)d_in[1];
    const int* dst = (const int*)d_in[2];
    const float* snorm_n = (const float*)d_in[3];
    const float* embed = (const float*)d_in[5];
    const float* Ws[3] = {(const float*)d_in[6], (const float*)d_in[11], (const float*)d_in[16]};
    const float* als[3] = {(const float*)d_in[7], (const float*)d_in[12], (const float*)d_in[17]};
    const float* ars[3] = {(const float*)d_in[8], (const float*)d_in[13], (const float*)d_in[18]};
    const float* gms[3] = {(const float*)d_in[9], (const float*)d_in[14], (const float*)d_in[19]};
    const float* bts[3] = {(const float*)d_in[10], (const float*)d_in[15], (const float*)d_in[20]};
    const float* cls1_w = (const float*)d_in[21];
    const float* cls1_b = (const float*)d_in[22];
    const float* cls2_w = (const float*)d_in[23];
    const float* cls2_b = (const float*)d_in[24];
    float* out = (float*)d_out;

    char* ws = (char*)d_ws;
    size_t off = 0;
    auto alloc = [&](size_t bytes) {
        void* p = ws + off;
        off = (off + bytes + 255) & ~(size_t)255;
        return p;
    };
    __half* h = (__half*)alloc((size_t)N_NODES * HDIM * 2);
    __half* feat_h = (__half*)alloc((size_t)N_NODES * HDIM * 2);
    float* el = (float*)alloc((size_t)N_NODES * 4 * 4);
    float* er = (float*)alloc((size_t)N_NODES * 4 * 4);
    int* rowstart = (int*)alloc((size_t)(N_NODES + 1) * 4);
    int* esrc = (int*)alloc((size_t)N_EDGES * 4);
    int* g_cursor = (int*)alloc((size_t)NB2 * 4);
    float* bn_part = (float*)alloc((size_t)3 * BN_BUCKETS * 256 * 4);
    __half* wpkh = (__half*)alloc((size_t)3 * 16384 * 2);
    unsigned* g_bucket = (unsigned*)alloc((size_t)NB2 * CAP * 4);  // 4 MB, NOT aliased (gemm0 || partB)
    (void)ws_size; (void)in_sizes; (void)n_in; (void)out_size;

    hipMemsetAsync(g_cursor, 0, NB2 * 4, stream);
    k_fuseA<<<GA + WPACK_BLOCKS, 1024, 0, stream>>>(src, dst, g_cursor, g_bucket,
                                                    Ws[0], Ws[1], Ws[2], wpkh, bn_part);
    k_fuseB<<<FUSEB_BLOCKS, 1024, 0, stream>>>(x, embed,
                                               reinterpret_cast<const f16x8*>(wpkh),
                                               feat_h, als[0], ars[0], el, er,
                                               g_bucket, g_cursor, rowstart, esrc);
    k_agg13<<<AGG_BLOCKS, 256, 0, stream>>>(feat_h, el, er, rowstart, esrc,
                                            snorm_n, h, bn_part, gms[0], bts[0],
                                            bn_part, 0);
    for (int L = 1; L < 3; L++) {
        const f16x8* wB = reinterpret_cast<const f16x8*>(wpkh + ((size_t)L << 14));
        const float* bn_prev = bn_part + (size_t)(L - 1) * BN_BUCKETS * 256;
        float* bn_cur = bn_part + (size_t)L * BN_BUCKETS * 256;
        k_gemm6<<<(N_NODES + 63) / 64, 256, 0, stream>>>(h, wB, feat_h,
                                                         bn_prev, gms[L - 1], bts[L - 1],
                                                         als[L], ars[L], el, er);
        k_agg13<<<AGG_BLOCKS, 256, 0, stream>>>(feat_h, el, er, rowstart, esrc,
                                                snorm_n, h, bn_prev, gms[L - 1], bts[L - 1],
                                                bn_cur, L);
    }

    k_classifier<<<(N_NODES + 15) / 16, 256, 0, stream>>>(h, cls1_w, cls1_b, cls2_w, cls2_b,
                                                          bn_part + (size_t)2 * BN_BUCKETS * 256,
                                                          gms[2], bts[2], out);
}

// Round 9
// 293.428 us; speedup vs baseline: 1.0625x; 1.0625x over previous
//
#include <hip/hip_runtime.h>
#include <hip/hip_bf16.h>
#include <hip/hip_fp16.h>
#include <math.h>

constexpr int N_NODES = 50000;
constexpr int N_EDGES = 850000;
constexpr int HDIM = 128;   // H*D
constexpr int AGG_BLOCKS = N_NODES / 8;  // 6250
constexpr int BN_BUCKETS = 16;

typedef _Float16 f16x8 __attribute__((ext_vector_type(8)));
typedef float f32x4 __attribute__((ext_vector_type(4)));

// v_fma_mix_f32: acc += f16(lo/hi of pk) * w   (exact f16->f32 convert inside FMA)
#define FMAMIX_LO(acc, pk, w) \
    asm("v_fma_mix_f32 %0, %1, %2, %0 op_sel:[0,0,0] op_sel_hi:[1,0,0]" \
        : "+v"(acc) : "v"(pk), "v"(w))
#define FMAMIX_HI(acc, pk, w) \
    asm("v_fma_mix_f32 %0, %1, %2, %0 op_sel:[1,0,0] op_sel_hi:[1,0,0]" \
        : "+v"(acc) : "v"(pk), "v"(w))

__device__ __forceinline__ float elu1(float t) {
    return (t > 0.f) ? t : (__expf(t) - 1.f);
}

// ---------------- CSR build params ----------------
constexpr int NB2 = 128;                                // buckets
constexpr int RANGE2 = (N_NODES + NB2 - 1) / NB2;       // 391 nodes/bucket
constexpr int CAP = 8192;                               // bucket capacity (avg 6641)
constexpr int CHUNK = 8192;                             // edges per phase-A block
constexpr int GA = (N_EDGES + CHUNK - 1) / CHUNK;       // 104 blocks
constexpr int WPACK_BLOCKS = 7;                          // 7*1024 = 7168 = 3*2048 + 1024(cls)
constexpr int GEMM0_BLOCKS = (N_NODES + 255) / 256;      // 196
constexpr int FUSEB_BLOCKS = GEMM0_BLOCKS + NB2;         // 324

// ---------------- fused dispatch A: partA (CSR phase 1) || wpack ----------------
__global__ void k_fuseA(const int* __restrict__ src, const int* __restrict__ dst,
                        int* __restrict__ g_cursor, unsigned* __restrict__ bucket,
                        const float* __restrict__ W0, const float* __restrict__ W1,
                        const float* __restrict__ W2, const float* __restrict__ cls1w,
                        __half* __restrict__ wpk, __half* __restrict__ wcls,
                        float* __restrict__ bn_part) {
    __shared__ int hist[NB2];
    int tid = threadIdx.x;
    if (blockIdx.x < GA) {
        // ---- partA: bucket edges by dst range ----
        int e0 = blockIdx.x * CHUNK;
        int e1 = min(e0 + CHUNK, N_EDGES);
        if (tid < NB2) hist[tid] = 0;
        __syncthreads();
        for (int i = e0 + tid; i < e1; i += 1024) {
            int d = dst[i];
            atomicAdd(&hist[d / RANGE2], 1);
        }
        __syncthreads();
        int base = 0;
        if (tid < NB2) base = atomicAdd(&g_cursor[tid], hist[tid]);
        __syncthreads();
        if (tid < NB2) hist[tid] = base;
        __syncthreads();
        for (int i = e0 + tid; i < e1; i += 1024) {
            int d = dst[i];
            int s = src[i];
            int b = d / RANGE2;
            int p = atomicAdd(&hist[b], 1);
            bucket[b * CAP + p] = (unsigned)s | ((unsigned)(d - b * RANGE2) << 16);
        }
    } else {
        // ---- wpack: W -> MFMA B-fragment layout; zero bn_part; pack cls1_w ----
        int gid = (blockIdx.x - GA) * 1024 + tid;  // [0, 7168)
        int z0 = gid * 8;
        if (z0 < 3 * BN_BUCKETS * 256) {
            float4 z = make_float4(0.f, 0.f, 0.f, 0.f);
            *reinterpret_cast<float4*>(&bn_part[z0]) = z;
            *reinterpret_cast<float4*>(&bn_part[z0 + 4]) = z;
        }
        if (gid < 3 * 2048) {
            int L = gid >> 11;
            int rem = gid & 2047;
            int ct = rem >> 8;
            int kc = (rem >> 6) & 3;
            int l = rem & 63;
            const float* W = (L == 0) ? W0 : ((L == 1) ? W1 : W2);
            int c = ct * 16 + (l & 15);
            int k0 = kc * 32 + (l >> 4) * 8;
            __half tmp[8];
#pragma unroll
            for (int j = 0; j < 8; j++) tmp[j] = __float2half(W[(k0 + j) * HDIM + c]);
            *reinterpret_cast<float4*>(&wpk[((size_t)L << 14) +
                                            ((size_t)(ct * 4 + kc) * 64 + l) * 8]) =
                *reinterpret_cast<float4*>(tmp);
        } else if (gid < 3 * 2048 + 1024) {
            // classifier W1 (128x64) -> 16 fragments
            int g2 = gid - 3 * 2048;       // [0,1024)
            int ct = g2 >> 8;              // 4 col-tiles (64 cols)
            int kc = (g2 >> 6) & 3;        // 4 K-chunks (K=128)
            int l = g2 & 63;
            int c = ct * 16 + (l & 15);
            int k0 = kc * 32 + (l >> 4) * 8;
            __half tmp[8];
#pragma unroll
            for (int j = 0; j < 8; j++) tmp[j] = __float2half(cls1w[(k0 + j) * 64 + c]);
            *reinterpret_cast<float4*>(&wcls[((size_t)(ct * 4 + kc) * 64 + l) * 8]) =
                *reinterpret_cast<float4*>(tmp);
        }
    }
}

// ---------------- fused dispatch B: gemm layer-0 (mode0, 256 nodes/block) || partB ----------------
__global__ void k_fuseB(const int* __restrict__ xidx, const float* __restrict__ embed,
                        const f16x8* __restrict__ wB, __half* __restrict__ feat_h,
                        const float* __restrict__ al, const float* __restrict__ ar,
                        float* __restrict__ el, float* __restrict__ er,
                        const unsigned* __restrict__ bucket, const int* __restrict__ cnts,
                        int* __restrict__ rowstart, int* __restrict__ esrc) {
    __shared__ __align__(16) char smem[16 * 16 * 136 * 2];  // 69.6 KB, aliased per branch
    int tid = threadIdx.x;
    if (blockIdx.x < GEMM0_BLOCKS) {
        // ---- gemm0: feat = embed[x] @ W0 (MFMA), fused el/er; 16 waves, 256 nodes ----
        __half (*sf)[16][136] = reinterpret_cast<__half (*)[16][136]>(smem);
        int w = tid >> 6, lane = tid & 63;
        int r = lane & 15, kg = lane >> 4;
        int wbase = blockIdx.x * 256 + w * 16;
        int n = wbase + r;
        bool ok = n < N_NODES;
        f16x8 aF[4];
#pragma unroll
        for (int kc = 0; kc < 4; kc++)
#pragma unroll
            for (int j = 0; j < 8; j++) aF[kc][j] = (_Float16)0.f;
        if (ok) {
            int xi = xidx[n];
            const float* ep = embed + (size_t)xi * HDIM;
#pragma unroll
            for (int kc = 0; kc < 4; kc++) {
                int c0 = kc * 32 + kg * 8;
                float4 e0 = *reinterpret_cast<const float4*>(ep + c0);
                float4 e1 = *reinterpret_cast<const float4*>(ep + c0 + 4);
                aF[kc][0] = (_Float16)e0.x; aF[kc][1] = (_Float16)e0.y;
                aF[kc][2] = (_Float16)e0.z; aF[kc][3] = (_Float16)e0.w;
                aF[kc][4] = (_Float16)e1.x; aF[kc][5] = (_Float16)e1.y;
                aF[kc][6] = (_Float16)e1.z; aF[kc][7] = (_Float16)e1.w;
            }
        }
        f32x4 acc[8] = {};
#pragma unroll
        for (int kc = 0; kc < 4; kc++) {
#pragma unroll
            for (int ct = 0; ct < 8; ct++) {
                f16x8 bF = wB[(ct * 4 + kc) * 64 + lane];
                acc[ct] = __builtin_amdgcn_mfma_f32_16x16x32_f16(aF[kc], bF, acc[ct], 0, 0, 0);
            }
        }
#pragma unroll
        for (int ct = 0; ct < 8; ct++)
#pragma unroll
            for (int reg = 0; reg < 4; reg++)
                sf[w][kg * 4 + reg][ct * 16 + r] = __float2half(acc[ct][reg]);
        __syncthreads();
        float alq[8], arq[8];
        {
            float4 a0 = *reinterpret_cast<const float4*>(&al[r * 8]);
            float4 a1 = *reinterpret_cast<const float4*>(&al[r * 8 + 4]);
            float4 b0 = *reinterpret_cast<const float4*>(&ar[r * 8]);
            float4 b1 = *reinterpret_cast<const float4*>(&ar[r * 8 + 4]);
            alq[0] = a0.x; alq[1] = a0.y; alq[2] = a0.z; alq[3] = a0.w;
            alq[4] = a1.x; alq[5] = a1.y; alq[6] = a1.z; alq[7] = a1.w;
            arq[0] = b0.x; arq[1] = b0.y; arq[2] = b0.z; arq[3] = b0.w;
            arq[4] = b1.x; arq[5] = b1.y; arq[6] = b1.z; arq[7] = b1.w;
        }
#pragma unroll
        for (int q = 0; q < 4; q++) {
            int row = q * 4 + kg;
            int n2 = wbase + row;
            float4 v = *reinterpret_cast<const float4*>(&sf[w][row][r * 8]);
            if (n2 < N_NODES)
                *reinterpret_cast<float4*>(&feat_h[(size_t)n2 * HDIM + r * 8]) = v;
            const __half2* u = reinterpret_cast<const __half2*>(&v);
            float pl = 0.f, pr = 0.f;
#pragma unroll
            for (int t = 0; t < 4; t++) {
                float lo = __half2float(__low2half(u[t]));
                float hi = __half2float(__high2half(u[t]));
                pl += lo * alq[2 * t] + hi * alq[2 * t + 1];
                pr += lo * arq[2 * t] + hi * arq[2 * t + 1];
            }
            pl += __shfl_xor(pl, 1, 64); pr += __shfl_xor(pr, 1, 64);
            pl += __shfl_xor(pl, 2, 64); pr += __shfl_xor(pr, 2, 64);
            if ((r & 3) == 0 && n2 < N_NODES) {
                int head = r >> 2;
                el[n2 * 4 + head] = pl;
                er[n2 * 4 + head] = pr;
            }
        }
    } else {
        // ---- partB: per-bucket counting sort -> rowstart/esrc ----
        int* cnt_s = reinterpret_cast<int*>(smem);            // 128
        int* hist = cnt_s + NB2;                               // 391
        int* lcur = hist + RANGE2;                             // 391
        int* wsum = lcur + RANGE2;                             // 7
        int b = blockIdx.x - GEMM0_BLOCKS;
        int lo = b * RANGE2;
        int myCount = cnts[b];
        if (tid < NB2) cnt_s[tid] = cnts[tid];
        __syncthreads();
        for (int off = 1; off < NB2; off <<= 1) {
            int t = (tid < NB2 && tid >= off) ? cnt_s[tid - off] : 0;
            __syncthreads();
            if (tid < NB2) cnt_s[tid] += t;
            __syncthreads();
        }
        int base = cnt_s[b] - myCount;
        for (int j = tid; j < RANGE2; j += 1024) hist[j] = 0;
        __syncthreads();
        const unsigned* my = bucket + (size_t)b * CAP;
        for (int i = tid; i < myCount; i += 1024) atomicAdd(&hist[my[i] >> 16], 1);
        __syncthreads();
        int v = 0;
        if (tid < 448) v = (tid < RANGE2) ? hist[tid] : 0;
        int inc = v;
        int lane = tid & 63;
#pragma unroll
        for (int off = 1; off < 64; off <<= 1) {
            int t = __shfl_up(inc, off, 64);
            if (lane >= off) inc += t;
        }
        if (tid < 448 && lane == 63) wsum[tid >> 6] = inc;
        __syncthreads();
        if (tid < RANGE2) {
            int woff = 0;
            for (int w = 0; w < (tid >> 6); w++) woff += wsum[w];
            int excl = woff + inc - v;
            lcur[tid] = excl;
            int node = lo + tid;
            if (node < N_NODES) rowstart[node] = base + excl;
        }
        if (b == 0 && tid == 0) rowstart[N_NODES] = N_EDGES;
        __syncthreads();
        for (int i = tid; i < myCount; i += 1024) {
            unsigned p = my[i];
            int pos = atomicAdd(&lcur[p >> 16], 1);
            esrc[base + pos] = (int)(p & 0xFFFFu);
        }
    }
}

// ---------------- GEMM v6: MFMA 16x16x32_f16, BN finalize fused in prologue (L1/L2) ----------------
__global__ void k_gemm6(const __half* __restrict__ h, const f16x8* __restrict__ wB,
                        __half* __restrict__ feat_h, const float* __restrict__ bn_prev,
                        const float* __restrict__ gamma, const float* __restrict__ beta,
                        const float* __restrict__ al, const float* __restrict__ ar,
                        float* __restrict__ el, float* __restrict__ er) {
    __shared__ __half sf[4][16][136];  // per-wave 16x128 fp16 tile (+8 pad), 17.4 KB
    __shared__ __align__(16) float s_sc[128];
    __shared__ __align__(16) float s_sh[128];
    int tid = threadIdx.x;
    // ---- BN finalize prologue (redundant per block; bn_prev is L2-resident 16 KB) ----
    {
        float* red = reinterpret_cast<float*>(sf);   // alias; sf written after
        int c = tid & 127, which = tid >> 7;
        float t = 0.f;
#pragma unroll
        for (int b = 0; b < BN_BUCKETS; b++) t += bn_prev[b * 256 + which * 128 + c];
        red[tid] = t;
        __syncthreads();
        if (tid < 128) {
            float mu = red[tid] * (1.f / N_NODES);
            float var = red[128 + tid] * (1.f / N_NODES) - mu * mu;
            float sc = gamma[tid] * rsqrtf(var + 1e-5f);
            s_sc[tid] = sc;
            s_sh[tid] = beta[tid] - mu * sc;
        }
        __syncthreads();
    }
    int w = tid >> 6, lane = tid & 63;
    int r = lane & 15, kg = lane >> 4;
    int wbase = blockIdx.x * 64 + w * 16;
    int n = wbase + r;
    bool ok = n < N_NODES;

    f16x8 aF[4];
#pragma unroll
    for (int kc = 0; kc < 4; kc++)
#pragma unroll
        for (int j = 0; j < 8; j++) aF[kc][j] = (_Float16)0.f;
    if (ok) {
        const __half* hp = h + (size_t)n * HDIM;
#pragma unroll
        for (int kc = 0; kc < 4; kc++) {
            int c0 = kc * 32 + kg * 8;
            float4 raw = *reinterpret_cast<const float4*>(hp + c0);
            const __half2* u = reinterpret_cast<const __half2*>(&raw);
            float4 sc0 = *reinterpret_cast<const float4*>(&s_sc[c0]);
            float4 sc1 = *reinterpret_cast<const float4*>(&s_sc[c0 + 4]);
            float4 sh0 = *reinterpret_cast<const float4*>(&s_sh[c0]);
            float4 sh1 = *reinterpret_cast<const float4*>(&s_sh[c0 + 4]);
            float scv[8] = {sc0.x, sc0.y, sc0.z, sc0.w, sc1.x, sc1.y, sc1.z, sc1.w};
            float shv[8] = {sh0.x, sh0.y, sh0.z, sh0.w, sh1.x, sh1.y, sh1.z, sh1.w};
            float vv[8];
#pragma unroll
            for (int t = 0; t < 4; t++) {
                vv[2 * t] = __half2float(__low2half(u[t]));
                vv[2 * t + 1] = __half2float(__high2half(u[t]));
            }
#pragma unroll
            for (int j = 0; j < 8; j++) {
                float t = vv[j] * scv[j] + shv[j];
                aF[kc][j] = (_Float16)elu1(t);
            }
        }
    }
    __syncthreads();  // red alias done before sf writes

    f32x4 acc[8] = {};
#pragma unroll
    for (int kc = 0; kc < 4; kc++) {
#pragma unroll
        for (int ct = 0; ct < 8; ct++) {
            f16x8 bF = wB[(ct * 4 + kc) * 64 + lane];
            acc[ct] = __builtin_amdgcn_mfma_f32_16x16x32_f16(aF[kc], bF, acc[ct], 0, 0, 0);
        }
    }

#pragma unroll
    for (int ct = 0; ct < 8; ct++)
#pragma unroll
        for (int reg = 0; reg < 4; reg++)
            sf[w][kg * 4 + reg][ct * 16 + r] = __float2half(acc[ct][reg]);
    __syncthreads();
    float alq[8], arq[8];
    {
        float4 a0 = *reinterpret_cast<const float4*>(&al[r * 8]);
        float4 a1 = *reinterpret_cast<const float4*>(&al[r * 8 + 4]);
        float4 b0 = *reinterpret_cast<const float4*>(&ar[r * 8]);
        float4 b1 = *reinterpret_cast<const float4*>(&ar[r * 8 + 4]);
        alq[0] = a0.x; alq[1] = a0.y; alq[2] = a0.z; alq[3] = a0.w;
        alq[4] = a1.x; alq[5] = a1.y; alq[6] = a1.z; alq[7] = a1.w;
        arq[0] = b0.x; arq[1] = b0.y; arq[2] = b0.z; arq[3] = b0.w;
        arq[4] = b1.x; arq[5] = b1.y; arq[6] = b1.z; arq[7] = b1.w;
    }
#pragma unroll
    for (int q = 0; q < 4; q++) {
        int row = q * 4 + kg;
        int n2 = wbase + row;
        float4 v = *reinterpret_cast<const float4*>(&sf[w][row][r * 8]);
        if (n2 < N_NODES)
            *reinterpret_cast<float4*>(&feat_h[(size_t)n2 * HDIM + r * 8]) = v;
        const __half2* u = reinterpret_cast<const __half2*>(&v);
        float pl = 0.f, pr = 0.f;
#pragma unroll
        for (int t = 0; t < 4; t++) {
            float lo = __half2float(__low2half(u[t]));
            float hi = __half2float(__high2half(u[t]));
            pl += lo * alq[2 * t] + hi * alq[2 * t + 1];
            pr += lo * arq[2 * t] + hi * arq[2 * t + 1];
        }
        pl += __shfl_xor(pl, 1, 64); pr += __shfl_xor(pr, 1, 64);
        pl += __shfl_xor(pl, 2, 64); pr += __shfl_xor(pr, 2, 64);
        if ((r & 3) == 0 && n2 < N_NODES) {
            int head = r >> 2;
            el[n2 * 4 + head] = pl;
            er[n2 * 4 + head] = pr;
        }
    }
}

// ---------------- aggregation v14: 4-deep remainder-free gather pipeline ----------------
// All 32 LDS slots per chunk are always written (w=0 beyond deg, clamped src index),
// so iters rounds up to a multiple of 4 (<=16): waste slots contribute exactly 0 and
// duplicate the last real row (L2 hits).
__global__ void k_agg14(const __half* __restrict__ feat_h, const float* __restrict__ el,
                        const float* __restrict__ er, const int* __restrict__ rowstart,
                        const int* __restrict__ esrc, const float* __restrict__ snorm_n,
                        __half* __restrict__ h, const float* __restrict__ bn_prev,
                        const float* __restrict__ gamma, const float* __restrict__ beta,
                        float* __restrict__ bn_cur, int layer) {
    __shared__ __align__(16) int2 lds[4][2][2][32][4];  // [wave][h2][buf][slot][head], 16 KB
    __shared__ __align__(16) float s_sc[128];
    __shared__ __align__(16) float s_sh[128];
    int tid = threadIdx.x;
    if (layer > 0) {
        float* red = reinterpret_cast<float*>(lds);  // alias; lds rewritten after barrier
        int c = tid & 127, which = tid >> 7;
        float t = 0.f;
#pragma unroll
        for (int b = 0; b < BN_BUCKETS; b++) t += bn_prev[b * 256 + which * 128 + c];
        red[tid] = t;
        __syncthreads();
        if (tid < 128) {
            float mu = red[tid] * (1.f / N_NODES);
            float var = red[128 + tid] * (1.f / N_NODES) - mu * mu;
            float sc = gamma[tid] * rsqrtf(var + 1e-5f);
            s_sc[tid] = sc;
            s_sh[tid] = beta[tid] - mu * sc;
        }
        __syncthreads();
    }
    int wave = tid >> 6, lane = tid & 63;
    int h2 = lane >> 5, hl = lane & 31;
    int dp = hl & 15, epair = hl >> 4, head = dp >> 2;
    unsigned dpo = (unsigned)dp << 4;
    const char* fb = reinterpret_cast<const char*>(feat_h);
    const char* eb = reinterpret_cast<const char*>(el);
    int n = blockIdx.x * 8 + wave * 2 + h2;
    int e0 = rowstart[n];
    int deg = rowstart[n + 1] - e0;
    int dmax = max(deg, __shfl_xor(deg, 32, 64));
    float4 er4 = *(const float4*)&er[n * 4];
    float s = 0.f;
    float a[8] = {};
    int nch = (dmax + 31) >> 5;

    int idx0 = e0 + min(hl, deg - 1);
    int sidx_p = esrc[idx0];
    float4 el_p = *reinterpret_cast<const float4*>(eb + ((unsigned)sidx_p << 4));
    bool val_p = hl < deg;

    for (int c = 0; c < nch; c++) {
        float w0 = 0.f, w1 = 0.f, w2 = 0.f, w3 = 0.f;
        int sv = sidx_p;
        if (val_p) {
            float ex = el_p.x + er4.x, ey = el_p.y + er4.y;
            float ez = el_p.z + er4.z, ew = el_p.w + er4.w;
            ex = fmaxf(ex, 0.f) + 0.2f * fminf(ex, 0.f);
            ey = fmaxf(ey, 0.f) + 0.2f * fminf(ey, 0.f);
            ez = fmaxf(ez, 0.f) + 0.2f * fminf(ez, 0.f);
            ew = fmaxf(ew, 0.f) + 0.2f * fminf(ew, 0.f);
            w0 = __expf(ex); w1 = __expf(ey); w2 = __expf(ez); w3 = __expf(ew);
        }
        int4* wp = reinterpret_cast<int4*>(&lds[wave][h2][c & 1][hl][0]);
        wp[0] = make_int4(sv, __float_as_int(w0), sv, __float_as_int(w1));
        wp[1] = make_int4(sv, __float_as_int(w2), sv, __float_as_int(w3));
        if (c + 1 < nch) {
            int slot = (c + 1) * 32 + hl;
            int idx = e0 + min(slot, deg - 1);
            sidx_p = esrc[idx];
            el_p = *reinterpret_cast<const float4*>(eb + ((unsigned)sidx_p << 4));
            val_p = slot < deg;
        }
        int cnt = min(32, dmax - c * 32);
        int iters = (cnt + 1) >> 1;          // pairs actually needed
        int itr4 = (iters + 3) & ~3;         // round up to 4; <=16, all slots valid
        const int2 (*slot_p)[4] = lds[wave][h2][c & 1];
#pragma unroll 1
        for (int j = 0; j < itr4; j += 4) {
            int2 rr[4];
#pragma unroll
            for (int q = 0; q < 4; q++) rr[q] = slot_p[(j + q) * 2 + epair][head];
            uint4 uu[4];
#pragma unroll
            for (int q = 0; q < 4; q++)
                uu[q] = *reinterpret_cast<const uint4*>(fb + (((unsigned)rr[q].x << 8) + dpo));
#pragma unroll
            for (int q = 0; q < 4; q++) {
                float w = __int_as_float(rr[q].y);
                FMAMIX_LO(a[0], uu[q].x, w); FMAMIX_HI(a[1], uu[q].x, w);
                FMAMIX_LO(a[2], uu[q].y, w); FMAMIX_HI(a[3], uu[q].y, w);
                FMAMIX_LO(a[4], uu[q].z, w); FMAMIX_HI(a[5], uu[q].z, w);
                FMAMIX_LO(a[6], uu[q].w, w); FMAMIX_HI(a[7], uu[q].w, w);
                s += w;
            }
        }
    }
#pragma unroll
    for (int k = 0; k < 8; k++) a[k] += __shfl_xor(a[k], 16, 64);
    s += __shfl_xor(s, 16, 64);
    float r[8] = {};
    if (epair == 0) {
        float inv = 1.f / s;
        int d0 = dp * 8;
#pragma unroll
        for (int k = 0; k < 8; k++) r[k] = a[k] * inv;
        if (layer > 0) {
            float4 hraw = *reinterpret_cast<const float4*>(&h[(size_t)n * HDIM + d0]);
            __half2 q0 = *(__half2*)&hraw.x, q1 = *(__half2*)&hraw.y;
            __half2 q2 = *(__half2*)&hraw.z, q3 = *(__half2*)&hraw.w;
            float hv[8] = {__half2float(__low2half(q0)), __half2float(__high2half(q0)),
                           __half2float(__low2half(q1)), __half2float(__high2half(q1)),
                           __half2float(__low2half(q2)), __half2float(__high2half(q2)),
                           __half2float(__low2half(q3)), __half2float(__high2half(q3))};
            float4 sc0 = *reinterpret_cast<const float4*>(&s_sc[d0]);
            float4 sc1 = *reinterpret_cast<const float4*>(&s_sc[d0 + 4]);
            float4 sh0 = *reinterpret_cast<const float4*>(&s_sh[d0]);
            float4 sh1 = *reinterpret_cast<const float4*>(&s_sh[d0 + 4]);
            float scv[8] = {sc0.x, sc0.y, sc0.z, sc0.w, sc1.x, sc1.y, sc1.z, sc1.w};
            float shv[8] = {sh0.x, sh0.y, sh0.z, sh0.w, sh1.x, sh1.y, sh1.z, sh1.w};
#pragma unroll
            for (int k = 0; k < 8; k++) {
                float t = hv[k] * scv[k] + shv[k];
                r[k] += elu1(t);
                r[k] = elu1(r[k]);
            }
        }
        float sn = snorm_n[n];
#pragma unroll
        for (int k = 0; k < 8; k++) r[k] *= sn;
        float4 outv;
        *(__half2*)&outv.x = __floats2half2_rn(r[0], r[1]);
        *(__half2*)&outv.y = __floats2half2_rn(r[2], r[3]);
        *(__half2*)&outv.z = __floats2half2_rn(r[4], r[5]);
        *(__half2*)&outv.w = __floats2half2_rn(r[6], r[7]);
        *reinterpret_cast<float4*>(&h[(size_t)n * HDIM + d0]) = outv;
    }

    float* bsum = reinterpret_cast<float*>(lds);
    __syncthreads();
    if (epair == 0) {
        int n8 = wave * 2 + h2;
        int cbase = n8 * 128 + dp * 8;
#pragma unroll
        for (int k = 0; k < 8; k++) {
            bsum[cbase + k] = r[k];
            bsum[1024 + cbase + k] = r[k] * r[k];
        }
    }
    __syncthreads();
    {
        int c = tid & 127, which = tid >> 7;
        float v = 0.f;
#pragma unroll
        for (int n8 = 0; n8 < 8; n8++) v += bsum[which * 1024 + n8 * 128 + c];
        atomicAdd(&bn_cur[(blockIdx.x & (BN_BUCKETS - 1)) * 256 + which * 128 + c], v);
    }
}

// ---------------- classifier v2: MFMA 16x16x32_f16, BN finalize fused ----------------
// 64 nodes/block, 4 waves. Per wave: 16 nodes x 64 hidden = 4 col-tiles x 4 K-chunks
// = 16 MFMA; epilogue relu + W2 (64x2) dot + 16-lane butterfly.
__global__ void k_classifier2(const __half* __restrict__ h, const f16x8* __restrict__ w1B,
                              const float* __restrict__ b1, const float* __restrict__ W2,
                              const float* __restrict__ b2, const float* __restrict__ bn_prev,
                              const float* __restrict__ gamma, const float* __restrict__ beta,
                              float* __restrict__ out) {
    __shared__ float red[256];
    __shared__ __align__(16) float s_sc[128];
    __shared__ __align__(16) float s_sh[128];
    int tid = threadIdx.x;
    {
        int c = tid & 127, which = tid >> 7;
        float t = 0.f;
#pragma unroll
        for (int b = 0; b < BN_BUCKETS; b++) t += bn_prev[b * 256 + which * 128 + c];
        red[tid] = t;
        __syncthreads();
        if (tid < 128) {
            float mu = red[tid] * (1.f / N_NODES);
            float var = red[128 + tid] * (1.f / N_NODES) - mu * mu;
            float sc = gamma[tid] * rsqrtf(var + 1e-5f);
            s_sc[tid] = sc;
            s_sh[tid] = beta[tid] - mu * sc;
        }
        __syncthreads();
    }
    int w = tid >> 6, lane = tid & 63;
    int r = lane & 15, kg = lane >> 4;
    int wbase = blockIdx.x * 64 + w * 16;
    int n = wbase + r;
    bool ok = n < N_NODES;

    f16x8 aF[4];
#pragma unroll
    for (int kc = 0; kc < 4; kc++)
#pragma unroll
        for (int j = 0; j < 8; j++) aF[kc][j] = (_Float16)0.f;
    if (ok) {
        const __half* hp = h + (size_t)n * HDIM;
#pragma unroll
        for (int kc = 0; kc < 4; kc++) {
            int c0 = kc * 32 + kg * 8;
            float4 raw = *reinterpret_cast<const float4*>(hp + c0);
            const __half2* u = reinterpret_cast<const __half2*>(&raw);
            float4 sc0 = *reinterpret_cast<const float4*>(&s_sc[c0]);
            float4 sc1 = *reinterpret_cast<const float4*>(&s_sc[c0 + 4]);
            float4 sh0 = *reinterpret_cast<const float4*>(&s_sh[c0]);
            float4 sh1 = *reinterpret_cast<const float4*>(&s_sh[c0 + 4]);
            float scv[8] = {sc0.x, sc0.y, sc0.z, sc0.w, sc1.x, sc1.y, sc1.z, sc1.w};
            float shv[8] = {sh0.x, sh0.y, sh0.z, sh0.w, sh1.x, sh1.y, sh1.z, sh1.w};
            float vv[8];
#pragma unroll
            for (int t = 0; t < 4; t++) {
                vv[2 * t] = __half2float(__low2half(u[t]));
                vv[2 * t + 1] = __half2float(__high2half(u[t]));
            }
#pragma unroll
            for (int j = 0; j < 8; j++) {
                float t = vv[j] * scv[j] + shv[j];
                aF[kc][j] = (_Float16)elu1(t);
            }
        }
    }

    f32x4 acc[4] = {};
#pragma unroll
    for (int kc = 0; kc < 4; kc++) {
#pragma unroll
        for (int ct = 0; ct < 4; ct++) {
            f16x8 bF = w1B[(ct * 4 + kc) * 64 + lane];
            acc[ct] = __builtin_amdgcn_mfma_f32_16x16x32_f16(aF[kc], bF, acc[ct], 0, 0, 0);
        }
    }

    // epilogue: hidden[row=kg*4+reg][col=ct*16+r]; relu + W2 dot + butterfly over r
    float b1q[4], w20q[4], w21q[4];
#pragma unroll
    for (int ct = 0; ct < 4; ct++) {
        int c = ct * 16 + r;
        b1q[ct] = b1[c];
        float2 w2v = *reinterpret_cast<const float2*>(&W2[c * 2]);
        w20q[ct] = w2v.x;
        w21q[ct] = w2v.y;
    }
    float b20 = b2[0], b21 = b2[1];
#pragma unroll
    for (int reg = 0; reg < 4; reg++) {
        float p0 = 0.f, p1 = 0.f;
#pragma unroll
        for (int ct = 0; ct < 4; ct++) {
            float hid = fmaxf(acc[ct][reg] + b1q[ct], 0.f);
            p0 += hid * w20q[ct];
            p1 += hid * w21q[ct];
        }
#pragma unroll
        for (int off = 1; off < 16; off <<= 1) {
            p0 += __shfl_xor(p0, off, 64);
            p1 += __shfl_xor(p1, off, 64);
        }
        if (r == 0) {
            int n2 = wbase + kg * 4 + reg;
            if (n2 < N_NODES) {
                out[n2 * 2] = p0 + b20;
                out[n2 * 2 + 1] = p1 + b21;
            }
        }
    }
}

// ----------------------------------------------------------------
extern "C" void kernel_launch(void* const* d_in, const int* in_sizes, int n_in,
                              void* d_out, int out_size, void* d_ws, size_t ws_size,
                              hipStream_t stream) {
    const int* x = (const int*)d_in[0];
    const int* src = (const int*)d_in[1];
    const int* dst = (const int*)d_in[2];
    const float* snorm_n = (const float*)d_in[3];
    const float* embed = (const float*)d_in[5];
    const float* Ws[3] = {(const float*)d_in[6], (const float*)d_in[11], (const float*)d_in[16]};
    const float* als[3] = {(const float*)d_in[7], (const float*)d_in[12], (const float*)d_in[17]};
    const float* ars[3] = {(const float*)d_in[8], (const float*)d_in[13], (const float*)d_in[18]};
    const float* gms[3] = {(const float*)d_in[9], (const float*)d_in[14], (const float*)d_in[19]};
    const float* bts[3] = {(const float*)d_in[10], (const float*)d_in[15], (const float*)d_in[20]};
    const float* cls1_w = (const float*)d_in[21];
    const float* cls1_b = (const float*)d_in[22];
    const float* cls2_w = (const float*)d_in[23];
    const float* cls2_b = (const float*)d_in[24];
    float* out = (float*)d_out;

    char* ws = (char*)d_ws;
    size_t off = 0;
    auto alloc = [&](size_t bytes) {
        void* p = ws + off;
        off = (off + bytes + 255) & ~(size_t)255;
        return p;
    };
    __half* h = (__half*)alloc((size_t)N_NODES * HDIM * 2);
    __half* feat_h = (__half*)alloc((size_t)N_NODES * HDIM * 2);
    float* el = (float*)alloc((size_t)N_NODES * 4 * 4);
    float* er = (float*)alloc((size_t)N_NODES * 4 * 4);
    int* rowstart = (int*)alloc((size_t)(N_NODES + 1) * 4);
    int* esrc = (int*)alloc((size_t)N_EDGES * 4);
    int* g_cursor = (int*)alloc((size_t)NB2 * 4);
    float* bn_part = (float*)alloc((size_t)3 * BN_BUCKETS * 256 * 4);
    __half* wpkh = (__half*)alloc((size_t)3 * 16384 * 2);
    __half* wcls = (__half*)alloc((size_t)8192 * 2);
    unsigned* g_bucket = (unsigned*)alloc((size_t)NB2 * CAP * 4);  // 4 MB, NOT aliased (gemm0 || partB)
    (void)ws_size; (void)in_sizes; (void)n_in; (void)out_size;

    hipMemsetAsync(g_cursor, 0, NB2 * 4, stream);
    k_fuseA<<<GA + WPACK_BLOCKS, 1024, 0, stream>>>(src, dst, g_cursor, g_bucket,
                                                    Ws[0], Ws[1], Ws[2], cls1_w,
                                                    wpkh, wcls, bn_part);
    k_fuseB<<<FUSEB_BLOCKS, 1024, 0, stream>>>(x, embed,
                                               reinterpret_cast<const f16x8*>(wpkh),
                                               feat_h, als[0], ars[0], el, er,
                                               g_bucket, g_cursor, rowstart, esrc);
    k_agg14<<<AGG_BLOCKS, 256, 0, stream>>>(feat_h, el, er, rowstart, esrc,
                                            snorm_n, h, bn_part, gms[0], bts[0],
                                            bn_part, 0);
    for (int L = 1; L < 3; L++) {
        const f16x8* wB = reinterpret_cast<const f16x8*>(wpkh + ((size_t)L << 14));
        const float* bn_prev = bn_part + (size_t)(L - 1) * BN_BUCKETS * 256;
        float* bn_cur = bn_part + (size_t)L * BN_BUCKETS * 256;
        k_gemm6<<<(N_NODES + 63) / 64, 256, 0, stream>>>(h, wB, feat_h,
                                                         bn_prev, gms[L - 1], bts[L - 1],
                                                         als[L], ars[L], el, er);
        k_agg14<<<AGG_BLOCKS, 256, 0, stream>>>(feat_h, el, er, rowstart, esrc,
                                                snorm_n, h, bn_prev, gms[L - 1], bts[L - 1],
                                                bn_cur, L);
    }

    k_classifier2<<<(N_NODES + 63) / 64, 256, 0, stream>>>(h,
                                                           reinterpret_cast<const f16x8*>(wcls),
                                                           cls1_b, cls2_w, cls2_b,
                                                           bn_part + (size_t)2 * BN_BUCKETS * 256,
                                                           gms[2], bts[2], out);
}

// Round 10
// 292.089 us; speedup vs baseline: 1.0674x; 1.0046x over previous
//
#include <hip/hip_runtime.h>
#include <hip/hip_bf16.h>
#include <hip/hip_fp16.h>
#include <math.h>

constexpr int N_NODES = 50000;
constexpr int N_EDGES = 850000;
constexpr int HDIM = 128;   // H*D
constexpr int AGG_BLOCKS = N_NODES / 8;  // 6250
constexpr int BN_BUCKETS = 16;

typedef _Float16 f16x8 __attribute__((ext_vector_type(8)));
typedef float f32x4 __attribute__((ext_vector_type(4)));

// v_fma_mix_f32: acc += f16(lo/hi of pk) * w   (exact f16->f32 convert inside FMA)
#define FMAMIX_LO(acc, pk, w) \
    asm("v_fma_mix_f32 %0, %1, %2, %0 op_sel:[0,0,0] op_sel_hi:[1,0,0]" \
        : "+v"(acc) : "v"(pk), "v"(w))
#define FMAMIX_HI(acc, pk, w) \
    asm("v_fma_mix_f32 %0, %1, %2, %0 op_sel:[1,0,0] op_sel_hi:[1,0,0]" \
        : "+v"(acc) : "v"(pk), "v"(w))

__device__ __forceinline__ float elu1(float t) {
    return (t > 0.f) ? t : (__expf(t) - 1.f);
}

// ---------------- CSR build params ----------------
constexpr int NB2 = 128;                                // buckets
constexpr int RANGE2 = (N_NODES + NB2 - 1) / NB2;       // 391 nodes/bucket
constexpr int CAP = 8192;                               // bucket capacity (avg 6641)
constexpr int CHUNK = 8192;                             // edges per phase-A block
constexpr int GA = (N_EDGES + CHUNK - 1) / CHUNK;       // 104 blocks
constexpr int WPACK_BLOCKS = 7;                          // 7*1024 = 7168 = 3*2048 + 1024(cls)
constexpr int GEMM0_BLOCKS = (N_NODES + 255) / 256;      // 196
constexpr int FUSEB_BLOCKS = GEMM0_BLOCKS + NB2;         // 324

// ---------------- fused dispatch A: partA (CSR phase 1) || wpack ----------------
__global__ void k_fuseA(const int* __restrict__ src, const int* __restrict__ dst,
                        int* __restrict__ g_cursor, unsigned* __restrict__ bucket,
                        const float* __restrict__ W0, const float* __restrict__ W1,
                        const float* __restrict__ W2, const float* __restrict__ cls1w,
                        __half* __restrict__ wpk, __half* __restrict__ wcls,
                        float* __restrict__ bn_part) {
    __shared__ int hist[NB2];
    int tid = threadIdx.x;
    if (blockIdx.x < GA) {
        // ---- partA: bucket edges by dst range ----
        int e0 = blockIdx.x * CHUNK;
        int e1 = min(e0 + CHUNK, N_EDGES);
        if (tid < NB2) hist[tid] = 0;
        __syncthreads();
        for (int i = e0 + tid; i < e1; i += 1024) {
            int d = dst[i];
            atomicAdd(&hist[d / RANGE2], 1);
        }
        __syncthreads();
        int base = 0;
        if (tid < NB2) base = atomicAdd(&g_cursor[tid], hist[tid]);
        __syncthreads();
        if (tid < NB2) hist[tid] = base;
        __syncthreads();
        for (int i = e0 + tid; i < e1; i += 1024) {
            int d = dst[i];
            int s = src[i];
            int b = d / RANGE2;
            int p = atomicAdd(&hist[b], 1);
            bucket[b * CAP + p] = (unsigned)s | ((unsigned)(d - b * RANGE2) << 16);
        }
    } else {
        // ---- wpack: W -> MFMA B-fragment layout; zero bn_part; pack cls1_w ----
        int gid = (blockIdx.x - GA) * 1024 + tid;  // [0, 7168)
        int z0 = gid * 8;
        if (z0 < 3 * BN_BUCKETS * 256) {
            float4 z = make_float4(0.f, 0.f, 0.f, 0.f);
            *reinterpret_cast<float4*>(&bn_part[z0]) = z;
            *reinterpret_cast<float4*>(&bn_part[z0 + 4]) = z;
        }
        if (gid < 3 * 2048) {
            int L = gid >> 11;
            int rem = gid & 2047;
            int ct = rem >> 8;
            int kc = (rem >> 6) & 3;
            int l = rem & 63;
            const float* W = (L == 0) ? W0 : ((L == 1) ? W1 : W2);
            int c = ct * 16 + (l & 15);
            int k0 = kc * 32 + (l >> 4) * 8;
            __half tmp[8];
#pragma unroll
            for (int j = 0; j < 8; j++) tmp[j] = __float2half(W[(k0 + j) * HDIM + c]);
            *reinterpret_cast<float4*>(&wpk[((size_t)L << 14) +
                                            ((size_t)(ct * 4 + kc) * 64 + l) * 8]) =
                *reinterpret_cast<float4*>(tmp);
        } else if (gid < 3 * 2048 + 1024) {
            // classifier W1 (128x64) -> 16 fragments
            int g2 = gid - 3 * 2048;       // [0,1024)
            int ct = g2 >> 8;              // 4 col-tiles (64 cols)
            int kc = (g2 >> 6) & 3;        // 4 K-chunks (K=128)
            int l = g2 & 63;
            int c = ct * 16 + (l & 15);
            int k0 = kc * 32 + (l >> 4) * 8;
            __half tmp[8];
#pragma unroll
            for (int j = 0; j < 8; j++) tmp[j] = __float2half(cls1w[(k0 + j) * 64 + c]);
            *reinterpret_cast<float4*>(&wcls[((size_t)(ct * 4 + kc) * 64 + l) * 8]) =
                *reinterpret_cast<float4*>(tmp);
        }
    }
}

// ---------------- fused dispatch B: gemm layer-0 (mode0, 256 nodes/block) || partB ----------------
__global__ void k_fuseB(const int* __restrict__ xidx, const float* __restrict__ embed,
                        const f16x8* __restrict__ wB, __half* __restrict__ feat_h,
                        const float* __restrict__ al, const float* __restrict__ ar,
                        float* __restrict__ el, float* __restrict__ er,
                        const unsigned* __restrict__ bucket, const int* __restrict__ cnts,
                        int* __restrict__ rowstart, int* __restrict__ esrc) {
    __shared__ __align__(16) char smem[16 * 16 * 136 * 2];  // 69.6 KB, aliased per branch
    int tid = threadIdx.x;
    if (blockIdx.x < GEMM0_BLOCKS) {
        // ---- gemm0: feat = embed[x] @ W0 (MFMA), fused el/er; 16 waves, 256 nodes ----
        __half (*sf)[16][136] = reinterpret_cast<__half (*)[16][136]>(smem);
        int w = tid >> 6, lane = tid & 63;
        int r = lane & 15, kg = lane >> 4;
        int wbase = blockIdx.x * 256 + w * 16;
        int n = wbase + r;
        bool ok = n < N_NODES;
        f16x8 aF[4];
#pragma unroll
        for (int kc = 0; kc < 4; kc++)
#pragma unroll
            for (int j = 0; j < 8; j++) aF[kc][j] = (_Float16)0.f;
        if (ok) {
            int xi = xidx[n];
            const float* ep = embed + (size_t)xi * HDIM;
#pragma unroll
            for (int kc = 0; kc < 4; kc++) {
                int c0 = kc * 32 + kg * 8;
                float4 e0 = *reinterpret_cast<const float4*>(ep + c0);
                float4 e1 = *reinterpret_cast<const float4*>(ep + c0 + 4);
                aF[kc][0] = (_Float16)e0.x; aF[kc][1] = (_Float16)e0.y;
                aF[kc][2] = (_Float16)e0.z; aF[kc][3] = (_Float16)e0.w;
                aF[kc][4] = (_Float16)e1.x; aF[kc][5] = (_Float16)e1.y;
                aF[kc][6] = (_Float16)e1.z; aF[kc][7] = (_Float16)e1.w;
            }
        }
        f32x4 acc[8] = {};
#pragma unroll
        for (int kc = 0; kc < 4; kc++) {
#pragma unroll
            for (int ct = 0; ct < 8; ct++) {
                f16x8 bF = wB[(ct * 4 + kc) * 64 + lane];
                acc[ct] = __builtin_amdgcn_mfma_f32_16x16x32_f16(aF[kc], bF, acc[ct], 0, 0, 0);
            }
        }
#pragma unroll
        for (int ct = 0; ct < 8; ct++)
#pragma unroll
            for (int reg = 0; reg < 4; reg++)
                sf[w][kg * 4 + reg][ct * 16 + r] = __float2half(acc[ct][reg]);
        __syncthreads();
        float alq[8], arq[8];
        {
            float4 a0 = *reinterpret_cast<const float4*>(&al[r * 8]);
            float4 a1 = *reinterpret_cast<const float4*>(&al[r * 8 + 4]);
            float4 b0 = *reinterpret_cast<const float4*>(&ar[r * 8]);
            float4 b1 = *reinterpret_cast<const float4*>(&ar[r * 8 + 4]);
            alq[0] = a0.x; alq[1] = a0.y; alq[2] = a0.z; alq[3] = a0.w;
            alq[4] = a1.x; alq[5] = a1.y; alq[6] = a1.z; alq[7] = a1.w;
            arq[0] = b0.x; arq[1] = b0.y; arq[2] = b0.z; arq[3] = b0.w;
            arq[4] = b1.x; arq[5] = b1.y; arq[6] = b1.z; arq[7] = b1.w;
        }
#pragma unroll
        for (int q = 0; q < 4; q++) {
            int row = q * 4 + kg;
            int n2 = wbase + row;
            float4 v = *reinterpret_cast<const float4*>(&sf[w][row][r * 8]);
            if (n2 < N_NODES)
                *reinterpret_cast<float4*>(&feat_h[(size_t)n2 * HDIM + r * 8]) = v;
            const __half2* u = reinterpret_cast<const __half2*>(&v);
            float pl = 0.f, pr = 0.f;
#pragma unroll
            for (int t = 0; t < 4; t++) {
                float lo = __half2float(__low2half(u[t]));
                float hi = __half2float(__high2half(u[t]));
                pl += lo * alq[2 * t] + hi * alq[2 * t + 1];
                pr += lo * arq[2 * t] + hi * arq[2 * t + 1];
            }
            pl += __shfl_xor(pl, 1, 64); pr += __shfl_xor(pr, 1, 64);
            pl += __shfl_xor(pl, 2, 64); pr += __shfl_xor(pr, 2, 64);
            if ((r & 3) == 0 && n2 < N_NODES) {
                int head = r >> 2;
                el[n2 * 4 + head] = pl;
                er[n2 * 4 + head] = pr;
            }
        }
    } else {
        // ---- partB: per-bucket counting sort -> rowstart/esrc ----
        int* cnt_s = reinterpret_cast<int*>(smem);            // 128
        int* hist = cnt_s + NB2;                               // 391
        int* lcur = hist + RANGE2;                             // 391
        int* wsum = lcur + RANGE2;                             // 7
        int b = blockIdx.x - GEMM0_BLOCKS;
        int lo = b * RANGE2;
        int myCount = cnts[b];
        if (tid < NB2) cnt_s[tid] = cnts[tid];
        __syncthreads();
        for (int off = 1; off < NB2; off <<= 1) {
            int t = (tid < NB2 && tid >= off) ? cnt_s[tid - off] : 0;
            __syncthreads();
            if (tid < NB2) cnt_s[tid] += t;
            __syncthreads();
        }
        int base = cnt_s[b] - myCount;
        for (int j = tid; j < RANGE2; j += 1024) hist[j] = 0;
        __syncthreads();
        const unsigned* my = bucket + (size_t)b * CAP;
        for (int i = tid; i < myCount; i += 1024) atomicAdd(&hist[my[i] >> 16], 1);
        __syncthreads();
        int v = 0;
        if (tid < 448) v = (tid < RANGE2) ? hist[tid] : 0;
        int inc = v;
        int lane = tid & 63;
#pragma unroll
        for (int off = 1; off < 64; off <<= 1) {
            int t = __shfl_up(inc, off, 64);
            if (lane >= off) inc += t;
        }
        if (tid < 448 && lane == 63) wsum[tid >> 6] = inc;
        __syncthreads();
        if (tid < RANGE2) {
            int woff = 0;
            for (int w = 0; w < (tid >> 6); w++) woff += wsum[w];
            int excl = woff + inc - v;
            lcur[tid] = excl;
            int node = lo + tid;
            if (node < N_NODES) rowstart[node] = base + excl;
        }
        if (b == 0 && tid == 0) rowstart[N_NODES] = N_EDGES;
        __syncthreads();
        for (int i = tid; i < myCount; i += 1024) {
            unsigned p = my[i];
            int pos = atomicAdd(&lcur[p >> 16], 1);
            esrc[base + pos] = (int)(p & 0xFFFFu);
        }
    }
}

// ---------------- GEMM v7: 16-wave (256 nodes/block), BN finalize amortized ----------------
__global__ void k_gemm7(const __half* __restrict__ h, const f16x8* __restrict__ wB,
                        __half* __restrict__ feat_h, const float* __restrict__ bn_prev,
                        const float* __restrict__ gamma, const float* __restrict__ beta,
                        const float* __restrict__ al, const float* __restrict__ ar,
                        float* __restrict__ el, float* __restrict__ er) {
    __shared__ __half sf[16][16][136];  // 16 waves x 16x128 fp16 tile (+8 pad), 69.6 KB
    __shared__ __align__(16) float s_sc[128];
    __shared__ __align__(16) float s_sh[128];
    int tid = threadIdx.x;
    // ---- BN finalize prologue (once per 256 nodes) ----
    {
        float* red = reinterpret_cast<float*>(sf);   // alias; sf written after barrier
        if (tid < 256) {
            int c = tid & 127, which = tid >> 7;
            float t = 0.f;
#pragma unroll
            for (int b = 0; b < BN_BUCKETS; b++) t += bn_prev[b * 256 + which * 128 + c];
            red[tid] = t;
        }
        __syncthreads();
        if (tid < 128) {
            float mu = red[tid] * (1.f / N_NODES);
            float var = red[128 + tid] * (1.f / N_NODES) - mu * mu;
            float sc = gamma[tid] * rsqrtf(var + 1e-5f);
            s_sc[tid] = sc;
            s_sh[tid] = beta[tid] - mu * sc;
        }
        __syncthreads();
    }
    int w = tid >> 6, lane = tid & 63;
    int r = lane & 15, kg = lane >> 4;
    int wbase = blockIdx.x * 256 + w * 16;
    int n = wbase + r;
    bool ok = n < N_NODES;

    f16x8 aF[4];
#pragma unroll
    for (int kc = 0; kc < 4; kc++)
#pragma unroll
        for (int j = 0; j < 8; j++) aF[kc][j] = (_Float16)0.f;
    if (ok) {
        const __half* hp = h + (size_t)n * HDIM;
#pragma unroll
        for (int kc = 0; kc < 4; kc++) {
            int c0 = kc * 32 + kg * 8;
            float4 raw = *reinterpret_cast<const float4*>(hp + c0);
            const __half2* u = reinterpret_cast<const __half2*>(&raw);
            float4 sc0 = *reinterpret_cast<const float4*>(&s_sc[c0]);
            float4 sc1 = *reinterpret_cast<const float4*>(&s_sc[c0 + 4]);
            float4 sh0 = *reinterpret_cast<const float4*>(&s_sh[c0]);
            float4 sh1 = *reinterpret_cast<const float4*>(&s_sh[c0 + 4]);
            float scv[8] = {sc0.x, sc0.y, sc0.z, sc0.w, sc1.x, sc1.y, sc1.z, sc1.w};
            float shv[8] = {sh0.x, sh0.y, sh0.z, sh0.w, sh1.x, sh1.y, sh1.z, sh1.w};
            float vv[8];
#pragma unroll
            for (int t = 0; t < 4; t++) {
                vv[2 * t] = __half2float(__low2half(u[t]));
                vv[2 * t + 1] = __half2float(__high2half(u[t]));
            }
#pragma unroll
            for (int j = 0; j < 8; j++) {
                float t = vv[j] * scv[j] + shv[j];
                aF[kc][j] = (_Float16)elu1(t);
            }
        }
    }
    __syncthreads();  // red alias fully consumed before sf writes

    f32x4 acc[8] = {};
#pragma unroll
    for (int kc = 0; kc < 4; kc++) {
#pragma unroll
        for (int ct = 0; ct < 8; ct++) {
            f16x8 bF = wB[(ct * 4 + kc) * 64 + lane];
            acc[ct] = __builtin_amdgcn_mfma_f32_16x16x32_f16(aF[kc], bF, acc[ct], 0, 0, 0);
        }
    }

#pragma unroll
    for (int ct = 0; ct < 8; ct++)
#pragma unroll
        for (int reg = 0; reg < 4; reg++)
            sf[w][kg * 4 + reg][ct * 16 + r] = __float2half(acc[ct][reg]);
    __syncthreads();
    float alq[8], arq[8];
    {
        float4 a0 = *reinterpret_cast<const float4*>(&al[r * 8]);
        float4 a1 = *reinterpret_cast<const float4*>(&al[r * 8 + 4]);
        float4 b0 = *reinterpret_cast<const float4*>(&ar[r * 8]);
        float4 b1 = *reinterpret_cast<const float4*>(&ar[r * 8 + 4]);
        alq[0] = a0.x; alq[1] = a0.y; alq[2] = a0.z; alq[3] = a0.w;
        alq[4] = a1.x; alq[5] = a1.y; alq[6] = a1.z; alq[7] = a1.w;
        arq[0] = b0.x; arq[1] = b0.y; arq[2] = b0.z; arq[3] = b0.w;
        arq[4] = b1.x; arq[5] = b1.y; arq[6] = b1.z; arq[7] = b1.w;
    }
#pragma unroll
    for (int q = 0; q < 4; q++) {
        int row = q * 4 + kg;
        int n2 = wbase + row;
        float4 v = *reinterpret_cast<const float4*>(&sf[w][row][r * 8]);
        if (n2 < N_NODES)
            *reinterpret_cast<float4*>(&feat_h[(size_t)n2 * HDIM + r * 8]) = v;
        const __half2* u = reinterpret_cast<const __half2*>(&v);
        float pl = 0.f, pr = 0.f;
#pragma unroll
        for (int t = 0; t < 4; t++) {
            float lo = __half2float(__low2half(u[t]));
            float hi = __half2float(__high2half(u[t]));
            pl += lo * alq[2 * t] + hi * alq[2 * t + 1];
            pr += lo * arq[2 * t] + hi * arq[2 * t + 1];
        }
        pl += __shfl_xor(pl, 1, 64); pr += __shfl_xor(pr, 1, 64);
        pl += __shfl_xor(pl, 2, 64); pr += __shfl_xor(pr, 2, 64);
        if ((r & 3) == 0 && n2 < N_NODES) {
            int head = r >> 2;
            el[n2 * 4 + head] = pl;
            er[n2 * 4 + head] = pr;
        }
    }
}

// ---------------- aggregation v14: 4-deep remainder-free gather pipeline ----------------
__global__ void k_agg14(const __half* __restrict__ feat_h, const float* __restrict__ el,
                        const float* __restrict__ er, const int* __restrict__ rowstart,
                        const int* __restrict__ esrc, const float* __restrict__ snorm_n,
                        __half* __restrict__ h, const float* __restrict__ bn_prev,
                        const float* __restrict__ gamma, const float* __restrict__ beta,
                        float* __restrict__ bn_cur, int layer) {
    __shared__ __align__(16) int2 lds[4][2][2][32][4];  // [wave][h2][buf][slot][head], 16 KB
    __shared__ __align__(16) float s_sc[128];
    __shared__ __align__(16) float s_sh[128];
    int tid = threadIdx.x;
    if (layer > 0) {
        float* red = reinterpret_cast<float*>(lds);  // alias; lds rewritten after barrier
        int c = tid & 127, which = tid >> 7;
        float t = 0.f;
#pragma unroll
        for (int b = 0; b < BN_BUCKETS; b++) t += bn_prev[b * 256 + which * 128 + c];
        red[tid] = t;
        __syncthreads();
        if (tid < 128) {
            float mu = red[tid] * (1.f / N_NODES);
            float var = red[128 + tid] * (1.f / N_NODES) - mu * mu;
            float sc = gamma[tid] * rsqrtf(var + 1e-5f);
            s_sc[tid] = sc;
            s_sh[tid] = beta[tid] - mu * sc;
        }
        __syncthreads();
    }
    int wave = tid >> 6, lane = tid & 63;
    int h2 = lane >> 5, hl = lane & 31;
    int dp = hl & 15, epair = hl >> 4, head = dp >> 2;
    unsigned dpo = (unsigned)dp << 4;
    const char* fb = reinterpret_cast<const char*>(feat_h);
    const char* eb = reinterpret_cast<const char*>(el);
    int n = blockIdx.x * 8 + wave * 2 + h2;
    int e0 = rowstart[n];
    int deg = rowstart[n + 1] - e0;
    int dmax = max(deg, __shfl_xor(deg, 32, 64));
    float4 er4 = *(const float4*)&er[n * 4];
    float s = 0.f;
    float a[8] = {};
    int nch = (dmax + 31) >> 5;

    int idx0 = e0 + min(hl, deg - 1);
    int sidx_p = esrc[idx0];
    float4 el_p = *reinterpret_cast<const float4*>(eb + ((unsigned)sidx_p << 4));
    bool val_p = hl < deg;

    for (int c = 0; c < nch; c++) {
        float w0 = 0.f, w1 = 0.f, w2 = 0.f, w3 = 0.f;
        int sv = sidx_p;
        if (val_p) {
            float ex = el_p.x + er4.x, ey = el_p.y + er4.y;
            float ez = el_p.z + er4.z, ew = el_p.w + er4.w;
            ex = fmaxf(ex, 0.f) + 0.2f * fminf(ex, 0.f);
            ey = fmaxf(ey, 0.f) + 0.2f * fminf(ey, 0.f);
            ez = fmaxf(ez, 0.f) + 0.2f * fminf(ez, 0.f);
            ew = fmaxf(ew, 0.f) + 0.2f * fminf(ew, 0.f);
            w0 = __expf(ex); w1 = __expf(ey); w2 = __expf(ez); w3 = __expf(ew);
        }
        int4* wp = reinterpret_cast<int4*>(&lds[wave][h2][c & 1][hl][0]);
        wp[0] = make_int4(sv, __float_as_int(w0), sv, __float_as_int(w1));
        wp[1] = make_int4(sv, __float_as_int(w2), sv, __float_as_int(w3));
        if (c + 1 < nch) {
            int slot = (c + 1) * 32 + hl;
            int idx = e0 + min(slot, deg - 1);
            sidx_p = esrc[idx];
            el_p = *reinterpret_cast<const float4*>(eb + ((unsigned)sidx_p << 4));
            val_p = slot < deg;
        }
        int cnt = min(32, dmax - c * 32);
        int iters = (cnt + 1) >> 1;          // pairs actually needed
        int itr4 = (iters + 3) & ~3;         // round up to 4; <=16, all slots valid
        const int2 (*slot_p)[4] = lds[wave][h2][c & 1];
#pragma unroll 1
        for (int j = 0; j < itr4; j += 4) {
            int2 rr[4];
#pragma unroll
            for (int q = 0; q < 4; q++) rr[q] = slot_p[(j + q) * 2 + epair][head];
            uint4 uu[4];
#pragma unroll
            for (int q = 0; q < 4; q++)
                uu[q] = *reinterpret_cast<const uint4*>(fb + (((unsigned)rr[q].x << 8) + dpo));
#pragma unroll
            for (int q = 0; q < 4; q++) {
                float w = __int_as_float(rr[q].y);
                FMAMIX_LO(a[0], uu[q].x, w); FMAMIX_HI(a[1], uu[q].x, w);
                FMAMIX_LO(a[2], uu[q].y, w); FMAMIX_HI(a[3], uu[q].y, w);
                FMAMIX_LO(a[4], uu[q].z, w); FMAMIX_HI(a[5], uu[q].z, w);
                FMAMIX_LO(a[6], uu[q].w, w); FMAMIX_HI(a[7], uu[q].w, w);
                s += w;
            }
        }
    }
#pragma unroll
    for (int k = 0; k < 8; k++) a[k] += __shfl_xor(a[k], 16, 64);
    s += __shfl_xor(s, 16, 64);
    float r[8] = {};
    if (epair == 0) {
        float inv = 1.f / s;
        int d0 = dp * 8;
#pragma unroll
        for (int k = 0; k < 8; k++) r[k] = a[k] * inv;
        if (layer > 0) {
            float4 hraw = *reinterpret_cast<const float4*>(&h[(size_t)n * HDIM + d0]);
            __half2 q0 = *(__half2*)&hraw.x, q1 = *(__half2*)&hraw.y;
            __half2 q2 = *(__half2*)&hraw.z, q3 = *(__half2*)&hraw.w;
            float hv[8] = {__half2float(__low2half(q0)), __half2float(__high2half(q0)),
                           __half2float(__low2half(q1)), __half2float(__high2half(q1)),
                           __half2float(__low2half(q2)), __half2float(__high2half(q2)),
                           __half2float(__low2half(q3)), __half2float(__high2half(q3))};
            float4 sc0 = *reinterpret_cast<const float4*>(&s_sc[d0]);
            float4 sc1 = *reinterpret_cast<const float4*>(&s_sc[d0 + 4]);
            float4 sh0 = *reinterpret_cast<const float4*>(&s_sh[d0]);
            float4 sh1 = *reinterpret_cast<const float4*>(&s_sh[d0 + 4]);
            float scv[8] = {sc0.x, sc0.y, sc0.z, sc0.w, sc1.x, sc1.y, sc1.z, sc1.w};
            float shv[8] = {sh0.x, sh0.y, sh0.z, sh0.w, sh1.x, sh1.y, sh1.z, sh1.w};
#pragma unroll
            for (int k = 0; k < 8; k++) {
                float t = hv[k] * scv[k] + shv[k];
                r[k] += elu1(t);
                r[k] = elu1(r[k]);
            }
        }
        float sn = snorm_n[n];
#pragma unroll
        for (int k = 0; k < 8; k++) r[k] *= sn;
        float4 outv;
        *(__half2*)&outv.x = __floats2half2_rn(r[0], r[1]);
        *(__half2*)&outv.y = __floats2half2_rn(r[2], r[3]);
        *(__half2*)&outv.z = __floats2half2_rn(r[4], r[5]);
        *(__half2*)&outv.w = __floats2half2_rn(r[6], r[7]);
        *reinterpret_cast<float4*>(&h[(size_t)n * HDIM + d0]) = outv;
    }

    float* bsum = reinterpret_cast<float*>(lds);
    __syncthreads();
    if (epair == 0) {
        int n8 = wave * 2 + h2;
        int cbase = n8 * 128 + dp * 8;
#pragma unroll
        for (int k = 0; k < 8; k++) {
            bsum[cbase + k] = r[k];
            bsum[1024 + cbase + k] = r[k] * r[k];
        }
    }
    __syncthreads();
    {
        int c = tid & 127, which = tid >> 7;
        float v = 0.f;
#pragma unroll
        for (int n8 = 0; n8 < 8; n8++) v += bsum[which * 1024 + n8 * 128 + c];
        atomicAdd(&bn_cur[(blockIdx.x & (BN_BUCKETS - 1)) * 256 + which * 128 + c], v);
    }
}

// ---------------- classifier v3: 16-wave (256 nodes/block), BN finalize amortized ----------------
__global__ void k_classifier3(const __half* __restrict__ h, const f16x8* __restrict__ w1B,
                              const float* __restrict__ b1, const float* __restrict__ W2,
                              const float* __restrict__ b2, const float* __restrict__ bn_prev,
                              const float* __restrict__ gamma, const float* __restrict__ beta,
                              float* __restrict__ out) {
    __shared__ float red[256];
    __shared__ __align__(16) float s_sc[128];
    __shared__ __align__(16) float s_sh[128];
    int tid = threadIdx.x;
    {
        if (tid < 256) {
            int c = tid & 127, which = tid >> 7;
            float t = 0.f;
#pragma unroll
            for (int b = 0; b < BN_BUCKETS; b++) t += bn_prev[b * 256 + which * 128 + c];
            red[tid] = t;
        }
        __syncthreads();
        if (tid < 128) {
            float mu = red[tid] * (1.f / N_NODES);
            float var = red[128 + tid] * (1.f / N_NODES) - mu * mu;
            float sc = gamma[tid] * rsqrtf(var + 1e-5f);
            s_sc[tid] = sc;
            s_sh[tid] = beta[tid] - mu * sc;
        }
        __syncthreads();
    }
    int w = tid >> 6, lane = tid & 63;
    int r = lane & 15, kg = lane >> 4;
    int wbase = blockIdx.x * 256 + w * 16;
    int n = wbase + r;
    bool ok = n < N_NODES;

    f16x8 aF[4];
#pragma unroll
    for (int kc = 0; kc < 4; kc++)
#pragma unroll
        for (int j = 0; j < 8; j++) aF[kc][j] = (_Float16)0.f;
    if (ok) {
        const __half* hp = h + (size_t)n * HDIM;
#pragma unroll
        for (int kc = 0; kc < 4; kc++) {
            int c0 = kc * 32 + kg * 8;
            float4 raw = *reinterpret_cast<const float4*>(hp + c0);
            const __half2* u = reinterpret_cast<const __half2*>(&raw);
            float4 sc0 = *reinterpret_cast<const float4*>(&s_sc[c0]);
            float4 sc1 = *reinterpret_cast<const float4*>(&s_sc[c0 + 4]);
            float4 sh0 = *reinterpret_cast<const float4*>(&s_sh[c0]);
            float4 sh1 = *reinterpret_cast<const float4*>(&s_sh[c0 + 4]);
            float scv[8] = {sc0.x, sc0.y, sc0.z, sc0.w, sc1.x, sc1.y, sc1.z, sc1.w};
            float shv[8] = {sh0.x, sh0.y, sh0.z, sh0.w, sh1.x, sh1.y, sh1.z, sh1.w};
            float vv[8];
#pragma unroll
            for (int t = 0; t < 4; t++) {
                vv[2 * t] = __half2float(__low2half(u[t]));
                vv[2 * t + 1] = __half2float(__high2half(u[t]));
            }
#pragma unroll
            for (int j = 0; j < 8; j++) {
                float t = vv[j] * scv[j] + shv[j];
                aF[kc][j] = (_Float16)elu1(t);
            }
        }
    }

    f32x4 acc[4] = {};
#pragma unroll
    for (int kc = 0; kc < 4; kc++) {
#pragma unroll
        for (int ct = 0; ct < 4; ct++) {
            f16x8 bF = w1B[(ct * 4 + kc) * 64 + lane];
            acc[ct] = __builtin_amdgcn_mfma_f32_16x16x32_f16(aF[kc], bF, acc[ct], 0, 0, 0);
        }
    }

    // epilogue: hidden[row=kg*4+reg][col=ct*16+r]; relu + W2 dot + butterfly over r
    float b1q[4], w20q[4], w21q[4];
#pragma unroll
    for (int ct = 0; ct < 4; ct++) {
        int c = ct * 16 + r;
        b1q[ct] = b1[c];
        float2 w2v = *reinterpret_cast<const float2*>(&W2[c * 2]);
        w20q[ct] = w2v.x;
        w21q[ct] = w2v.y;
    }
    float b20 = b2[0], b21 = b2[1];
#pragma unroll
    for (int reg = 0; reg < 4; reg++) {
        float p0 = 0.f, p1 = 0.f;
#pragma unroll
        for (int ct = 0; ct < 4; ct++) {
            float hid = fmaxf(acc[ct][reg] + b1q[ct], 0.f);
            p0 += hid * w20q[ct];
            p1 += hid * w21q[ct];
        }
#pragma unroll
        for (int off = 1; off < 16; off <<= 1) {
            p0 += __shfl_xor(p0, off, 64);
            p1 += __shfl_xor(p1, off, 64);
        }
        if (r == 0) {
            int n2 = wbase + kg * 4 + reg;
            if (n2 < N_NODES) {
                out[n2 * 2] = p0 + b20;
                out[n2 * 2 + 1] = p1 + b21;
            }
        }
    }
}

// ----------------------------------------------------------------
extern "C" void kernel_launch(void* const* d_in, const int* in_sizes, int n_in,
                              void* d_out, int out_size, void* d_ws, size_t ws_size,
                              hipStream_t stream) {
    const int* x = (const int*)d_in[0];
    const int* src = (const int*)d_in[1];
    const int* dst = (const int*)d_in[2];
    const float* snorm_n = (const float*)d_in[3];
    const float* embed = (const float*)d_in[5];
    const float* Ws[3] = {(const float*)d_in[6], (const float*)d_in[11], (const float*)d_in[16]};
    const float* als[3] = {(const float*)d_in[7], (const float*)d_in[12], (const float*)d_in[17]};
    const float* ars[3] = {(const float*)d_in[8], (const float*)d_in[13], (const float*)d_in[18]};
    const float* gms[3] = {(const float*)d_in[9], (const float*)d_in[14], (const float*)d_in[19]};
    const float* bts[3] = {(const float*)d_in[10], (const float*)d_in[15], (const float*)d_in[20]};
    const float* cls1_w = (const float*)d_in[21];
    const float* cls1_b = (const float*)d_in[22];
    const float* cls2_w = (const float*)d_in[23];
    const float* cls2_b = (const float*)d_in[24];
    float* out = (float*)d_out;

    char* ws = (char*)d_ws;
    size_t off = 0;
    auto alloc = [&](size_t bytes) {
        void* p = ws + off;
        off = (off + bytes + 255) & ~(size_t)255;
        return p;
    };
    __half* h = (__half*)alloc((size_t)N_NODES * HDIM * 2);
    __half* feat_h = (__half*)alloc((size_t)N_NODES * HDIM * 2);
    float* el = (float*)alloc((size_t)N_NODES * 4 * 4);
    float* er = (float*)alloc((size_t)N_NODES * 4 * 4);
    int* rowstart = (int*)alloc((size_t)(N_NODES + 1) * 4);
    int* esrc = (int*)alloc((size_t)N_EDGES * 4);
    int* g_cursor = (int*)alloc((size_t)NB2 * 4);
    float* bn_part = (float*)alloc((size_t)3 * BN_BUCKETS * 256 * 4);
    __half* wpkh = (__half*)alloc((size_t)3 * 16384 * 2);
    __half* wcls = (__half*)alloc((size_t)8192 * 2);
    unsigned* g_bucket = (unsigned*)alloc((size_t)NB2 * CAP * 4);  // 4 MB, NOT aliased (gemm0 || partB)
    (void)ws_size; (void)in_sizes; (void)n_in; (void)out_size;

    hipMemsetAsync(g_cursor, 0, NB2 * 4, stream);
    k_fuseA<<<GA + WPACK_BLOCKS, 1024, 0, stream>>>(src, dst, g_cursor, g_bucket,
                                                    Ws[0], Ws[1], Ws[2], cls1_w,
                                                    wpkh, wcls, bn_part);
    k_fuseB<<<FUSEB_BLOCKS, 1024, 0, stream>>>(x, embed,
                                               reinterpret_cast<const f16x8*>(wpkh),
                                               feat_h, als[0], ars[0], el, er,
                                               g_bucket, g_cursor, rowstart, esrc);
    k_agg14<<<AGG_BLOCKS, 256, 0, stream>>>(feat_h, el, er, rowstart, esrc,
                                            snorm_n, h, bn_part, gms[0], bts[0],
                                            bn_part, 0);
    for (int L = 1; L < 3; L++) {
        const f16x8* wB = reinterpret_cast<const f16x8*>(wpkh + ((size_t)L << 14));
        const float* bn_prev = bn_part + (size_t)(L - 1) * BN_BUCKETS * 256;
        float* bn_cur = bn_part + (size_t)L * BN_BUCKETS * 256;
        k_gemm7<<<GEMM0_BLOCKS, 1024, 0, stream>>>(h, wB, feat_h,
                                                   bn_prev, gms[L - 1], bts[L - 1],
                                                   als[L], ars[L], el, er);
        k_agg14<<<AGG_BLOCKS, 256, 0, stream>>>(feat_h, el, er, rowstart, esrc,
                                                snorm_n, h, bn_prev, gms[L - 1], bts[L - 1],
                                                bn_cur, L);
    }

    k_classifier3<<<GEMM0_BLOCKS, 1024, 0, stream>>>(h,
                                                     reinterpret_cast<const f16x8*>(wcls),
                                                     cls1_b, cls2_w, cls2_b,
                                                     bn_part + (size_t)2 * BN_BUCKETS * 256,
                                                     gms[2], bts[2], out);
}